// Round 16
// baseline (559.040 us; speedup 1.0000x reference)
//
#include <hip/hip_runtime.h>
#include <cstdint>
#include <cstddef>

#define ROADN 200000
#define NEDGE 1600000
#define NSEDGE 1000000
#define NP1 512    // partial buffers for T1
#define NP2 1024   // partial buffers for T2
#define PSPLIT 16  // p-axis split for the partial reduce
#define T2PAD 40   // ushorts per transposed-LDS row (80B: 16B-aligned, 2-way banks)
#define WXPAD 264  // k_x LDS col stride in ushorts (132 dw == 4 mod 32 -> conflict-free b128)

typedef __attribute__((ext_vector_type(8))) short s16x8;
typedef __attribute__((ext_vector_type(4))) float f32x4;

union FragU { int i[4]; s16x8 s; };

// split 8 f32 -> bf16 hi + bf16 lo fragments. PROVEN R3/R5. v_cvt_pk low=src0
// (proven: R3/R5 hi/lo residuals would be O(1) garbage under a swap).
__device__ inline void cvt_split8(const float v[8], s16x8& hi, s16x8& lo) {
  FragU H, L;
  float lof[8];
#pragma unroll
  for (int p = 0; p < 4; ++p) {
    int h;
    asm("v_cvt_pk_bf16_f32 %0, %1, %2" : "=v"(h) : "v"(v[2 * p]), "v"(v[2 * p + 1]));
    H.i[p] = h;
    float h0 = __builtin_bit_cast(float, (unsigned)h << 16);
    float h1 = __builtin_bit_cast(float, (unsigned)h & 0xFFFF0000u);
    lof[2 * p] = v[2 * p] - h0;
    lof[2 * p + 1] = v[2 * p + 1] - h1;
  }
#pragma unroll
  for (int p = 0; p < 4; ++p) {
    int l;
    asm("v_cvt_pk_bf16_f32 %0, %1, %2" : "=v"(l) : "v"(lof[2 * p]), "v"(lof[2 * p + 1]));
    L.i[p] = l;
  }
  hi = H.s; lo = L.s;
}

// 8 f32 -> bf16 hi-only, slot j = v[j] (identity; low=src0 proven)
__device__ inline s16x8 cvt8_hi(const float v[8]) {
  FragU F;
#pragma unroll
  for (int p = 0; p < 4; ++p) {
    int h;
    asm("v_cvt_pk_bf16_f32 %0, %1, %2" : "=v"(h) : "v"(v[2 * p]), "v"(v[2 * p + 1]));
    F.i[p] = h;
  }
  return F.s;
}

// single f32 -> bf16 (rne, same rounding as cvt_pk's low slot)
__device__ inline ushort cvt1_bf16(float v) {
  float z = 0.f;
  int h;
  asm("v_cvt_pk_bf16_f32 %0, %1, %2" : "=v"(h) : "v"(v), "v"(z));
  return (ushort)(h & 0xFFFF);
}

// ---------------- fused: Abf = bf16(A) + column sums of A ----------------
__global__ __launch_bounds__(256) void k_abf(const float* __restrict__ A,
                                             ushort* __restrict__ Abf,
                                             float* __restrict__ cs) {
  __shared__ float csl[128];
  int t = threadIdx.x;
  if (t < 128) csl[t] = 0.f;
  __syncthreads();
  float ps[8] = {0.f, 0.f, 0.f, 0.f, 0.f, 0.f, 0.f, 0.f};
  const size_t ngroups = (size_t)ROADN * 128 / 8;   // 3,200,000
  for (size_t g = blockIdx.x * 256ull + threadIdx.x; g < ngroups;
       g += (size_t)gridDim.x * 256ull) {
    const float* p = A + g * 8;
    float4 u0 = *reinterpret_cast<const float4*>(p);
    float4 u1 = *reinterpret_cast<const float4*>(p + 4);
    float v[8] = {u0.x, u0.y, u0.z, u0.w, u1.x, u1.y, u1.z, u1.w};
#pragma unroll
    for (int j = 0; j < 8; ++j) ps[j] += v[j];
    s16x8 h = cvt8_hi(v);
    *reinterpret_cast<s16x8*>(Abf + g * 8) = h;
  }
  int cb = (t * 8) & 127;
#pragma unroll
  for (int j = 0; j < 8; ++j)
    atomicAdd(&csl[cb + j], ps[j]);
  __syncthreads();
  if (t < 128) atomicAdd(&cs[t], csl[t]);
}

// ---------------- T2 partials: sum_e outer(A[dst_e], A[src_e]) --------------
// Double-buffered LDS pipeline: tile t+1's global gathers are issued right
// after tile t's registers are committed to LDS, hiding gather latency under
// tile t's MFMAs. ONE barrier per tile (write@t to buf[cur] is safe: readers
// of buf[cur] from tile t-2 finished before barrier(t-1)). Operand bits and
// MFMA order identical to R15 -> bit-identical numerics.
__global__ __launch_bounds__(256, 4) void k_t2(const ushort* __restrict__ Abf,
                                               const int* __restrict__ ei,
                                               float* __restrict__ PT2) {
  __shared__ ushort Td[2][128 * T2PAD];
  __shared__ ushort Ts[2][128 * T2PAD];
  int t = threadIdx.x;
  int w = t >> 6, l = t & 63;
  int lg = l >> 4, lc = l & 15;
  int rp = t & 15;        // row-pair 0..15 (rows 2rp, 2rp+1)
  int seg = t >> 4;       // 16B segment 0..15 (cols seg*8 .. seg*8+7)
  const int tiles = NEDGE / 32;                 // 50000
  const int tpb = (tiles + NP2 - 1) / NP2;      // 49
  int t0 = blockIdx.x * tpb;
  int t1e = min(t0 + tpb, tiles);

  f32x4 acc[8][2];
#pragma unroll
  for (int m = 0; m < 8; ++m)
#pragma unroll
    for (int n = 0; n < 2; ++n) acc[m][n] = (f32x4){0.f, 0.f, 0.f, 0.f};

  s16x8 vd0, vd1, vs0, vs1;   // in-flight tile registers
#define T2_LOAD(tt)                                                          \
  {                                                                          \
    int ebase = (tt) * 32;                                                   \
    int2 dd = *reinterpret_cast<const int2*>(ei + ebase + 2 * rp);           \
    int2 ss = *reinterpret_cast<const int2*>(ei + NEDGE + ebase + 2 * rp);   \
    vd0 = *reinterpret_cast<const s16x8*>(Abf + (size_t)dd.x * 128 + seg * 8); \
    vd1 = *reinterpret_cast<const s16x8*>(Abf + (size_t)dd.y * 128 + seg * 8); \
    vs0 = *reinterpret_cast<const s16x8*>(Abf + (size_t)ss.x * 128 + seg * 8); \
    vs1 = *reinterpret_cast<const s16x8*>(Abf + (size_t)ss.y * 128 + seg * 8); \
  }

  if (t0 < t1e) T2_LOAD(t0);
  int cur = 0;
  for (int tt = t0; tt < t1e; ++tt) {
    // commit in-flight tile to buf[cur] (transposed u32 writes, low = even row)
#pragma unroll
    for (int i = 0; i < 8; ++i) {
      unsigned pd = ((unsigned)(ushort)vd0[i]) | (((unsigned)(ushort)vd1[i]) << 16);
      unsigned ps = ((unsigned)(ushort)vs0[i]) | (((unsigned)(ushort)vs1[i]) << 16);
      int c = seg * 8 + i;
      *reinterpret_cast<unsigned*>(&Td[cur][c * T2PAD + 2 * rp]) = pd;
      *reinterpret_cast<unsigned*>(&Ts[cur][c * T2PAD + 2 * rp]) = ps;
    }
    // issue next tile's gathers (latency hides under this tile's compute)
    if (tt + 1 < t1e) T2_LOAD(tt + 1);
    __syncthreads();   // buf[cur] ready for all waves
    s16x8 bh[2];
#pragma unroll
    for (int n = 0; n < 2; ++n)
      bh[n] = *reinterpret_cast<const s16x8*>(
          &Ts[cur][(w * 32 + n * 16 + lc) * T2PAD + lg * 8]);
#pragma unroll
    for (int m = 0; m < 8; ++m) {
      s16x8 ah = *reinterpret_cast<const s16x8*>(
          &Td[cur][(m * 16 + lc) * T2PAD + lg * 8]);
#pragma unroll
      for (int n = 0; n < 2; ++n)
        acc[m][n] = __builtin_amdgcn_mfma_f32_16x16x32_bf16(ah, bh[n], acc[m][n], 0, 0, 0);
    }
    cur ^= 1;
  }
#undef T2_LOAD
  float* out = PT2 + (size_t)blockIdx.x * 16384;
#pragma unroll
  for (int m = 0; m < 8; ++m)
#pragma unroll
    for (int n = 0; n < 2; ++n)
#pragma unroll
      for (int r = 0; r < 4; ++r) {
        int row = m * 16 + lg * 4 + r;
        int col = (2 * w + n) * 16 + lc;
        out[row * 128 + col] = acc[m][n][r];
      }
}

// ---------------- T1 partials: A^T @ raw via MFMA (R5 verbatim) ----------------
__global__ __launch_bounds__(256) void k_t1(
    const float* __restrict__ A,
    const int* __restrict__ lf, const int* __restrict__ nf,
    const float* __restrict__ lemb, const float* __restrict__ nemb,
    float* __restrict__ PT1) {
  int t = threadIdx.x;
  int w = t >> 6, l = t & 63;
  int lg = l >> 4, lc = l & 15;
  const int tiles = ROADN / 32;                 // 6250
  const int tpb = (tiles + NP1 - 1) / NP1;      // 13
  int t0 = blockIdx.x * tpb;
  int t1e = min(t0 + tpb, tiles);

  f32x4 acc[8][2];
#pragma unroll
  for (int m = 0; m < 8; ++m)
#pragma unroll
    for (int n = 0; n < 2; ++n) acc[m][n] = (f32x4){0.f, 0.f, 0.f, 0.f};

  const int* idxp = (w == 0) ? lf : nf;

  for (int tt = t0; tt < t1e; ++tt) {
    int roff = tt * 32 + lg * 8;
    int4 i0 = *reinterpret_cast<const int4*>(idxp + roff);
    int4 i1 = *reinterpret_cast<const int4*>(idxp + roff + 4);
    int iv[8] = {i0.x, i0.y, i0.z, i0.w, i1.x, i1.y, i1.z, i1.w};
    const float* ap[8];
    const float* bp[8];
#pragma unroll
    for (int e = 0; e < 8; ++e) {
      ap[e] = A + (size_t)(roff + e) * 128 + lc;
      bp[e] = (w == 0) ? (lemb + (size_t)iv[e] * 32 + lc)
                       : (nemb + (size_t)iv[e] * 96 + (w * 32 - 32) + lc);
    }
    s16x8 bhi[2], blo[2];
#pragma unroll
    for (int n = 0; n < 2; ++n) {
      float bv[8];
#pragma unroll
      for (int e = 0; e < 8; ++e) bv[e] = bp[e][n * 16];
      cvt_split8(bv, bhi[n], blo[n]);
    }
#pragma unroll
    for (int m = 0; m < 8; ++m) {
      float av[8];
#pragma unroll
      for (int e = 0; e < 8; ++e) av[e] = ap[e][m * 16];
      s16x8 ahi, alo;
      cvt_split8(av, ahi, alo);
#pragma unroll
      for (int n = 0; n < 2; ++n) {
        acc[m][n] = __builtin_amdgcn_mfma_f32_16x16x32_bf16(ahi, bhi[n], acc[m][n], 0, 0, 0);
        acc[m][n] = __builtin_amdgcn_mfma_f32_16x16x32_bf16(ahi, blo[n], acc[m][n], 0, 0, 0);
        acc[m][n] = __builtin_amdgcn_mfma_f32_16x16x32_bf16(alo, bhi[n], acc[m][n], 0, 0, 0);
      }
    }
  }
  float* out = PT1 + (size_t)blockIdx.x * 16384;
#pragma unroll
  for (int m = 0; m < 8; ++m)
#pragma unroll
    for (int n = 0; n < 2; ++n)
#pragma unroll
      for (int r = 0; r < 4; ++r) {
        int row = m * 16 + lg * 4 + r;
        int col = (2 * w + n) * 16 + lc;
        out[row * 128 + col] = acc[m][n][r];
      }
}

// ---------------- reduce partials -> T1, T2 (p-split, high occupancy) --------
__global__ __launch_bounds__(256) void k_reduce(const float* __restrict__ PT1,
                                                const float* __restrict__ PT2,
                                                float* __restrict__ T1,
                                                float* __restrict__ T2) {
  int b = blockIdx.x;
  int which = b & 1;
  int echunk = (b >> 1) & 63;
  int pchunk = b >> 7;                        // 0..PSPLIT-1
  const float* P = which ? PT2 : PT1;
  int np = which ? NP2 : NP1;
  int ppc = np / PSPLIT;
  int e = echunk * 256 + threadIdx.x;
  const float* base = P + (size_t)pchunk * ppc * 16384 + e;
  float s = 0.f;
  for (int p = 0; p < ppc; ++p)
    s += base[(size_t)p * 16384];
  atomicAdd((which ? T2 : T1) + e, s);
}

// ---------------- all tiny 128x128 ops -> W12 [128,100] ----------------
#define ACC4(crow, lv, r4) \
  crow[0] += (lv) * (r4).x; crow[1] += (lv) * (r4).y; \
  crow[2] += (lv) * (r4).z; crow[3] += (lv) * (r4).w;

__global__ __launch_bounds__(1024) void k_small(
    const float* __restrict__ T1, const float* __restrict__ T2,
    const float* __restrict__ cs, const float* __restrict__ gcn_w,
    const float* __restrict__ gcn_b, const float* __restrict__ lin_w,
    float* __restrict__ Gg, float* __restrict__ FEg,
    float* __restrict__ W12) {
  __shared__ float SE[128 * 128];
  __shared__ float FA[128 * 128];
  __shared__ float sc[128];
  int t = threadIdx.x;
  int ty = t >> 5, tx = t & 31;
  if (t < 128) {
    float s = cs[t] - 1.f;
    sc[t] = 1.f / (fmaxf(s, 0.f) + 1.f);
  }
  __syncthreads();
  for (int idx = t; idx < 16384; idx += 1024)
    SE[idx] = sc[idx >> 7] * T1[idx];
  __syncthreads();
  // Gg = D * (SE @ gcn_w)
  {
    float c0[4] = {0,0,0,0}, c1[4] = {0,0,0,0}, c2[4] = {0,0,0,0}, c3[4] = {0,0,0,0};
    for (int m = 0; m < 128; ++m) {
      float4 r = *reinterpret_cast<const float4*>(gcn_w + m * 128 + tx * 4);
      float l0 = SE[(ty * 4 + 0) * 128 + m];
      float l1 = SE[(ty * 4 + 1) * 128 + m];
      float l2 = SE[(ty * 4 + 2) * 128 + m];
      float l3 = SE[(ty * 4 + 3) * 128 + m];
      ACC4(c0, l0, r); ACC4(c1, l1, r); ACC4(c2, l2, r); ACC4(c3, l3, r);
    }
    float* cr[4] = {c0, c1, c2, c3};
#pragma unroll
    for (int a = 0; a < 4; ++a) {
      int i = ty * 4 + a;
      float4 o = make_float4(sc[i]*cr[a][0], sc[i]*cr[a][1], sc[i]*cr[a][2], sc[i]*cr[a][3]);
      *reinterpret_cast<float4*>(Gg + i * 128 + tx * 4) = o;
    }
  }
  __syncthreads();
  // FA = H = D*(T2 @ Gg) + gcn_b
  {
    float c0[4] = {0,0,0,0}, c1[4] = {0,0,0,0}, c2[4] = {0,0,0,0}, c3[4] = {0,0,0,0};
    for (int m = 0; m < 128; ++m) {
      float4 r = *reinterpret_cast<const float4*>(Gg + m * 128 + tx * 4);
      float l0 = T2[(ty * 4 + 0) * 128 + m];
      float l1 = T2[(ty * 4 + 1) * 128 + m];
      float l2 = T2[(ty * 4 + 2) * 128 + m];
      float l3 = T2[(ty * 4 + 3) * 128 + m];
      ACC4(c0, l0, r); ACC4(c1, l1, r); ACC4(c2, l2, r); ACC4(c3, l3, r);
    }
    float4 b4 = *reinterpret_cast<const float4*>(gcn_b + tx * 4);
    float* cr[4] = {c0, c1, c2, c3};
#pragma unroll
    for (int a = 0; a < 4; ++a) {
      int i = ty * 4 + a;
      FA[i * 128 + tx * 4 + 0] = sc[i] * cr[a][0] + b4.x;
      FA[i * 128 + tx * 4 + 1] = sc[i] * cr[a][1] + b4.y;
      FA[i * 128 + tx * 4 + 2] = sc[i] * cr[a][2] + b4.z;
      FA[i * 128 + tx * 4 + 3] = sc[i] * cr[a][3] + b4.w;
    }
  }
  __syncthreads();
  if (t < 128) {
    int j = t;
    float mx = -3.4e38f;
    for (int i = 0; i < 128; ++i) mx = fmaxf(mx, FA[i * 128 + j]);
    float sum = 0.f;
    for (int i = 0; i < 128; ++i) {
      float e = expf(FA[i * 128 + j] - mx);
      FA[i * 128 + j] = e;
      sum += e;
    }
    float inv = 1.f / sum;
    for (int i = 0; i < 128; ++i) FA[i * 128 + j] *= inv;
  }
  __syncthreads();
  // FEg = FA^T @ SE
  {
    float c0[4] = {0,0,0,0}, c1[4] = {0,0,0,0}, c2[4] = {0,0,0,0}, c3[4] = {0,0,0,0};
    for (int m = 0; m < 128; ++m) {
      float4 r = *reinterpret_cast<const float4*>(&SE[m * 128 + tx * 4]);
      float l0 = FA[m * 128 + ty * 4 + 0];
      float l1 = FA[m * 128 + ty * 4 + 1];
      float l2 = FA[m * 128 + ty * 4 + 2];
      float l3 = FA[m * 128 + ty * 4 + 3];
      ACC4(c0, l0, r); ACC4(c1, l1, r); ACC4(c2, l2, r); ACC4(c3, l3, r);
    }
    float* cr[4] = {c0, c1, c2, c3};
#pragma unroll
    for (int a = 0; a < 4; ++a) {
      float4 o = make_float4(cr[a][0], cr[a][1], cr[a][2], cr[a][3]);
      *reinterpret_cast<float4*>(FEg + (ty * 4 + a) * 128 + tx * 4) = o;
    }
  }
  __syncthreads();
  // FF = FA @ FEg  (then FA <- FF)
  {
    float c0[4] = {0,0,0,0}, c1[4] = {0,0,0,0}, c2[4] = {0,0,0,0}, c3[4] = {0,0,0,0};
    for (int m = 0; m < 128; ++m) {
      float4 r = *reinterpret_cast<const float4*>(FEg + m * 128 + tx * 4);
      float l0 = FA[(ty * 4 + 0) * 128 + m];
      float l1 = FA[(ty * 4 + 1) * 128 + m];
      float l2 = FA[(ty * 4 + 2) * 128 + m];
      float l3 = FA[(ty * 4 + 3) * 128 + m];
      ACC4(c0, l0, r); ACC4(c1, l1, r); ACC4(c2, l2, r); ACC4(c3, l3, r);
    }
    __syncthreads();
    float* cr[4] = {c0, c1, c2, c3};
#pragma unroll
    for (int a = 0; a < 4; ++a) {
      int i = ty * 4 + a;
      FA[i * 128 + tx * 4 + 0] = cr[a][0];
      FA[i * 128 + tx * 4 + 1] = cr[a][1];
      FA[i * 128 + tx * 4 + 2] = cr[a][2];
      FA[i * 128 + tx * 4 + 3] = cr[a][3];
    }
  }
  __syncthreads();
  // W12[k][c] = sc[k] * sum_j (SE[k][j]*lin_w[128+j][c] + FA[k][j]*lin_w[256+j][c])
  if (tx < 25) {
    float c0[4] = {0,0,0,0}, c1[4] = {0,0,0,0}, c2[4] = {0,0,0,0}, c3[4] = {0,0,0,0};
    for (int j = 0; j < 128; ++j) {
      float4 r1 = *reinterpret_cast<const float4*>(lin_w + (128 + j) * 100 + tx * 4);
      float4 r2 = *reinterpret_cast<const float4*>(lin_w + (256 + j) * 100 + tx * 4);
      float s0 = SE[(ty * 4 + 0) * 128 + j], f0 = FA[(ty * 4 + 0) * 128 + j];
      float s1 = SE[(ty * 4 + 1) * 128 + j], f1 = FA[(ty * 4 + 1) * 128 + j];
      float s2 = SE[(ty * 4 + 2) * 128 + j], f2 = FA[(ty * 4 + 2) * 128 + j];
      float s3 = SE[(ty * 4 + 3) * 128 + j], f3 = FA[(ty * 4 + 3) * 128 + j];
      ACC4(c0, s0, r1); ACC4(c0, f0, r2);
      ACC4(c1, s1, r1); ACC4(c1, f1, r2);
      ACC4(c2, s2, r1); ACC4(c2, f2, r2);
      ACC4(c3, s3, r1); ACC4(c3, f3, r2);
    }
    float* cr[4] = {c0, c1, c2, c3};
#pragma unroll
    for (int a = 0; a < 4; ++a) {
      int k = ty * 4 + a;
#pragma unroll
      for (int b = 0; b < 4; ++b)
        W12[k * 100 + tx * 4 + b] = sc[k] * cr[a][b];
    }
  }
}

// ---------------- WThi/WTlo[col][k] bf16: padded transpose of [W0; W12] -----
__global__ __launch_bounds__(256) void k_wt(const float* __restrict__ lin_w,
                                            const float* __restrict__ W12,
                                            ushort* __restrict__ WThi,
                                            ushort* __restrict__ WTlo) {
  int idx = blockIdx.x * 256 + threadIdx.x;   // 0..28671
  if (idx >= 112 * 256) return;
  int col = idx >> 8;
  int k = idx & 255;
  float v = 0.f;
  if (col < 100)
    v = (k < 128) ? lin_w[k * 100 + col] : W12[(k - 128) * 100 + col];
  float z = 0.f;
  int h;
  asm("v_cvt_pk_bf16_f32 %0, %1, %2" : "=v"(h) : "v"(v), "v"(z));
  ushort hu = (ushort)(h & 0xFFFF);
  float hf = __builtin_bit_cast(float, (unsigned)hu << 16);
  float lof = v - hf;
  int lw2;
  asm("v_cvt_pk_bf16_f32 %0, %1, %2" : "=v"(lw2) : "v"(lof), "v"(z));
  WThi[idx] = hu;
  WTlo[idx] = (ushort)(lw2 & 0xFFFF);
}

// ---------------- X = in[200000,256] @ W[256,112pad] + b via MFMA ------------
// R14 structure + additional bf16 gather table Xbf[200000][128] (cols 100-111
// zeroed; 112-127 never read) for k_pred. X f32 output unchanged.
__global__ __launch_bounds__(1024, 4) void k_x(
    const float* __restrict__ A, const int* __restrict__ lf,
    const int* __restrict__ nf, const float* __restrict__ lemb,
    const float* __restrict__ nemb, const float* __restrict__ lin_b,
    const ushort* __restrict__ WThi, const ushort* __restrict__ WTlo,
    float* __restrict__ X, ushort* __restrict__ Xbf) {
  __shared__ ushort Whl[2][112 * WXPAD];
  int t = threadIdx.x;
  for (int i = t; i < 112 * 256; i += 1024) {
    int col = i >> 8;
    int k = i & 255;
    int d = col * WXPAD + k;
    Whl[0][d] = WThi[i];
    Whl[1][d] = WTlo[i];
  }
  __syncthreads();

  int wid = t >> 6, l = t & 63;
  int lg = l >> 4, lc = l & 15;
  int rb0 = blockIdx.x * 512 + wid * 32;     // this wave's 32 rows
  if (rb0 >= ROADN) return;                  // after the only barrier

  float bias[7];
#pragma unroll
  for (int n = 0; n < 7; ++n) {
    int c = n * 16 + lc;
    bias[n] = (c < 100) ? lin_b[c] : 0.f;
  }

  f32x4 acc[2][7];
#pragma unroll
  for (int m = 0; m < 2; ++m)
#pragma unroll
    for (int n = 0; n < 7; ++n) acc[m][n] = (f32x4){0.f, 0.f, 0.f, 0.f};

  int rr[2], lfv[2], nfv[2];
#pragma unroll
  for (int m = 0; m < 2; ++m) {
    int r = rb0 + m * 16 + lc;
    rr[m] = min(r, ROADN - 1);
    lfv[m] = lf[rr[m]];
    nfv[m] = nf[rr[m]];
  }

#pragma unroll
  for (int ks = 0; ks < 8; ++ks) {
    int kk = ks * 32;
    s16x8 ahi[2], alo[2];
#pragma unroll
    for (int m = 0; m < 2; ++m) {
      const float* p;
      if (ks == 0)
        p = lemb + (size_t)lfv[m] * 32 + lg * 8;
      else if (ks < 4)
        p = nemb + (size_t)nfv[m] * 96 + (kk - 32) + lg * 8;
      else
        p = A + (size_t)rr[m] * 128 + (kk - 128) + lg * 8;
      float4 u0 = *reinterpret_cast<const float4*>(p);
      float4 u1 = *reinterpret_cast<const float4*>(p + 4);
      float av[8] = {u0.x, u0.y, u0.z, u0.w, u1.x, u1.y, u1.z, u1.w};
      cvt_split8(av, ahi[m], alo[m]);
    }
#pragma unroll
    for (int n = 0; n < 7; ++n) {
      int off = (n * 16 + lc) * WXPAD + kk + lg * 8;
      s16x8 bh = *reinterpret_cast<const s16x8*>(&Whl[0][off]);
      s16x8 bl = *reinterpret_cast<const s16x8*>(&Whl[1][off]);
#pragma unroll
      for (int m = 0; m < 2; ++m) {
        acc[m][n] = __builtin_amdgcn_mfma_f32_16x16x32_bf16(ahi[m], bh, acc[m][n], 0, 0, 0);
        acc[m][n] = __builtin_amdgcn_mfma_f32_16x16x32_bf16(ahi[m], bl, acc[m][n], 0, 0, 0);
        acc[m][n] = __builtin_amdgcn_mfma_f32_16x16x32_bf16(alo[m], bh, acc[m][n], 0, 0, 0);
      }
    }
  }
  // store: C/D layout col = lane&15, row = (lane>>4)*4 + reg
#pragma unroll
  for (int m = 0; m < 2; ++m)
#pragma unroll
    for (int n = 0; n < 7; ++n) {
      int col = n * 16 + lc;
#pragma unroll
      for (int r4 = 0; r4 < 4; ++r4) {
        int row = rb0 + m * 16 + lg * 4 + r4;
        if (row < ROADN) {
          float v = acc[m][n][r4] + bias[n];
          if (col < 100) {
            X[(size_t)row * 100 + col] = v;
            Xbf[(size_t)row * 128 + col] = cvt1_bf16(v);
          } else {
            Xbf[(size_t)row * 128 + col] = 0;   // pad cols 100..111
          }
        }
      }
    }
}

// ---------------- pred[e] = dot(Xbf[se0[e]], Xbf[se1[e]]) (bf16 gathers) -----
__global__ __launch_bounds__(256) void k_pred(const ushort* __restrict__ Xbf,
                                              const int* __restrict__ se,
                                              float* __restrict__ out) {
  unsigned tid = blockIdx.x * 256u + threadIdx.x;
  unsigned e = tid >> 5, lane = tid & 31;
  int ra = se[e];
  int rb = se[NSEDGE + e];
  float acc = 0.f;
  if (lane < 28) {
    const ushort* xa = Xbf + (size_t)ra * 128 + lane * 4;
    const ushort* xb = Xbf + (size_t)rb * 128 + lane * 4;
    ushort4 a = *reinterpret_cast<const ushort4*>(xa);
    ushort4 b = *reinterpret_cast<const ushort4*>(xb);
    float ax = __builtin_bit_cast(float, (unsigned)a.x << 16);
    float ay = __builtin_bit_cast(float, (unsigned)a.y << 16);
    float az = __builtin_bit_cast(float, (unsigned)a.z << 16);
    float aw = __builtin_bit_cast(float, (unsigned)a.w << 16);
    float bx = __builtin_bit_cast(float, (unsigned)b.x << 16);
    float by = __builtin_bit_cast(float, (unsigned)b.y << 16);
    float bz = __builtin_bit_cast(float, (unsigned)b.z << 16);
    float bw = __builtin_bit_cast(float, (unsigned)b.w << 16);
    acc = ax * bx + ay * by + az * bz + aw * bw;
  }
#pragma unroll
  for (int off = 16; off > 0; off >>= 1)
    acc += __shfl_xor(acc, off, 32);
  if (lane == 0) out[e] = acc;
}

extern "C" void kernel_launch(void* const* d_in, const int* in_sizes, int n_in,
                              void* d_out, int out_size, void* d_ws, size_t ws_size,
                              hipStream_t stream) {
  const int*   lf   = (const int*)d_in[0];
  const int*   nf   = (const int*)d_in[1];
  const int*   ei   = (const int*)d_in[2];
  const float* A    = (const float*)d_in[3];
  const int*   se   = (const int*)d_in[4];
  const float* nemb = (const float*)d_in[5];
  const float* lemb = (const float*)d_in[6];
  const float* gw   = (const float*)d_in[7];
  const float* gb   = (const float*)d_in[8];
  const float* lw   = (const float*)d_in[9];
  const float* lb   = (const float*)d_in[10];

  float* ws  = (float*)d_ws;
  float* PT1 = ws;                           // 512*16384  = 8,388,608
  float* PT2 = PT1 + (size_t)NP1 * 16384;    // 1024*16384 = 16,777,216
  float* T1  = PT2 + (size_t)NP2 * 16384;    // 16,384
  float* T2  = T1 + 16384;                   // 16,384
  float* cs  = T2 + 16384;                   // 128
  float* Gg  = cs + 128;                     // 16,384
  float* FEg = Gg + 16384;                   // 16,384
  float* W12 = FEg + 16384;                  // 12,800
  ushort* WThi = (ushort*)(W12 + 12800);     // 28,672 ushorts (16B-aligned)
  ushort* WTlo = WThi + 112 * 256;           // 28,672 ushorts

  float* pred = (float*)d_out;
  float* X    = pred + NSEDGE;
  // Abf lives in the X region of d_out (overwritten by k_x each launch).
  ushort* Abf = (ushort*)X;
  // Xbf (25.6M ushorts = 51.2 MB) lives in the PT1/PT2 region, which is dead
  // after k_reduce and fully rewritten by k_t1/k_t2 next launch.
  ushort* Xbf = (ushort*)PT1;

  // zero T1, T2, cs (contiguous; atomically accumulated)
  hipMemsetAsync(T1, 0, (size_t)(16384 * 2 + 128) * sizeof(float), stream);

  k_abf<<<2048, 256, 0, stream>>>(A, Abf, cs);
  k_t1<<<NP1, 256, 0, stream>>>(A, lf, nf, lemb, nemb, PT1);
  k_t2<<<NP2, 256, 0, stream>>>(Abf, ei, PT2);
  k_reduce<<<2 * 64 * PSPLIT, 256, 0, stream>>>(PT1, PT2, T1, T2);
  k_small<<<1, 1024, 0, stream>>>(T1, T2, cs, gw, gb, lw, Gg, FEg, W12);
  k_wt<<<112, 256, 0, stream>>>(lw, W12, WThi, WTlo);
  k_x<<<(ROADN + 511) / 512, 1024, 0, stream>>>(A, lf, nf, lemb, nemb, lb, WThi, WTlo, X, Xbf);
  k_pred<<<(NSEDGE * 32) / 256, 256, 0, stream>>>(Xbf, se, pred);
}

// Round 17
// 528.560 us; speedup vs baseline: 1.0577x; 1.0577x over previous
//
#include <hip/hip_runtime.h>
#include <cstdint>
#include <cstddef>

#define ROADN 200000
#define NEDGE 1600000
#define NSEDGE 1000000
#define NP1 512    // partial buffers for T1
#define NP2 1024   // partial buffers for T2
#define PSPLIT 16  // p-axis split for the partial reduce
#define T8PAD 40   // BYTES per transposed-LDS col (8B-aligned b64 reads, conflict-free)
#define WXPAD 264  // k_x LDS col stride in ushorts (132 dw == 4 mod 32 -> conflict-free b128)

typedef __attribute__((ext_vector_type(8))) short s16x8;
typedef __attribute__((ext_vector_type(4))) float f32x4;

union FragU { int i[4]; s16x8 s; };
union Byte16 { s16x8 v; unsigned char b[16]; };

// split 8 f32 -> bf16 hi + bf16 lo fragments. PROVEN R3/R5. v_cvt_pk low=src0
// (proven: R3/R5 hi/lo residuals would be O(1) garbage under a swap).
__device__ inline void cvt_split8(const float v[8], s16x8& hi, s16x8& lo) {
  FragU H, L;
  float lof[8];
#pragma unroll
  for (int p = 0; p < 4; ++p) {
    int h;
    asm("v_cvt_pk_bf16_f32 %0, %1, %2" : "=v"(h) : "v"(v[2 * p]), "v"(v[2 * p + 1]));
    H.i[p] = h;
    float h0 = __builtin_bit_cast(float, (unsigned)h << 16);
    float h1 = __builtin_bit_cast(float, (unsigned)h & 0xFFFF0000u);
    lof[2 * p] = v[2 * p] - h0;
    lof[2 * p + 1] = v[2 * p + 1] - h1;
  }
#pragma unroll
  for (int p = 0; p < 4; ++p) {
    int l;
    asm("v_cvt_pk_bf16_f32 %0, %1, %2" : "=v"(l) : "v"(lof[2 * p]), "v"(lof[2 * p + 1]));
    L.i[p] = l;
  }
  hi = H.s; lo = L.s;
}

// single f32 -> bf16 (rne, same rounding as cvt_pk's low slot)
__device__ inline ushort cvt1_bf16(float v) {
  float z = 0.f;
  int h;
  asm("v_cvt_pk_bf16_f32 %0, %1, %2" : "=v"(h) : "v"(v), "v"(z));
  return (ushort)(h & 0xFFFF);
}

// ---------------- fused: Abf8 = fp8_e4m3(A) + column sums of A ----------------
// Identity byte order: group element j -> byte j (pk low: src0->b0,src1->b1;
// pk high: src0->b2,src1->b3). Both MFMA operands in k_t2 are staged from this
// table by pure byte moves -> consistent k-axis on A and B sides.
__global__ __launch_bounds__(256) void k_abf(const float* __restrict__ A,
                                             unsigned char* __restrict__ Abf8,
                                             float* __restrict__ cs) {
  __shared__ float csl[128];
  int t = threadIdx.x;
  if (t < 128) csl[t] = 0.f;
  __syncthreads();
  float ps[8] = {0.f, 0.f, 0.f, 0.f, 0.f, 0.f, 0.f, 0.f};
  const size_t ngroups = (size_t)ROADN * 128 / 8;   // 3,200,000
  for (size_t g = blockIdx.x * 256ull + threadIdx.x; g < ngroups;
       g += (size_t)gridDim.x * 256ull) {
    const float* p = A + g * 8;
    float4 u0 = *reinterpret_cast<const float4*>(p);
    float4 u1 = *reinterpret_cast<const float4*>(p + 4);
    float v[8] = {u0.x, u0.y, u0.z, u0.w, u1.x, u1.y, u1.z, u1.w};
#pragma unroll
    for (int j = 0; j < 8; ++j) ps[j] += v[j];
    int p0 = __builtin_amdgcn_cvt_pk_fp8_f32(v[0], v[1], 0, false);
    p0 = __builtin_amdgcn_cvt_pk_fp8_f32(v[2], v[3], p0, true);
    int p1 = __builtin_amdgcn_cvt_pk_fp8_f32(v[4], v[5], 0, false);
    p1 = __builtin_amdgcn_cvt_pk_fp8_f32(v[6], v[7], p1, true);
    int2 pk = make_int2(p0, p1);
    *reinterpret_cast<int2*>(Abf8 + g * 8) = pk;
  }
  int cb = (t * 8) & 127;
#pragma unroll
  for (int j = 0; j < 8; ++j)
    atomicAdd(&csl[cb + j], ps[j]);
  __syncthreads();
  if (t < 128) atomicAdd(&cs[t], csl[t]);
}

// ---------------- T2 partials: sum_e outer(A[dst_e], A[src_e]), fp8 ---------
// R16 double-buffer pipeline, element = 1 byte. LDS T[col][edge] (pad 40 B);
// frag read = one b64 (8 fp8 = K-slice, identity slot order both operands).
// MFMA = f32_16x16x32_fp8_fp8, same shape & C/D layout as the bf16 version.
__global__ __launch_bounds__(256, 4) void k_t2(const unsigned char* __restrict__ Abf8,
                                               const int* __restrict__ ei,
                                               float* __restrict__ PT2) {
  __shared__ unsigned char Td8[2][128 * T8PAD];
  __shared__ unsigned char Ts8[2][128 * T8PAD];
  int t = threadIdx.x;
  int w = t >> 6, l = t & 63;
  int lg = l >> 4, lc = l & 15;
  int half = t >> 7;          // 0: dst rows, 1: src rows
  int rp = t & 15;            // row-pair (rows 2rp, 2rp+1)
  int sg = (t >> 4) & 7;      // 16B segment (cols sg*16 .. sg*16+15)
  const int* eibase = ei + (size_t)half * NEDGE;
  const int tiles = NEDGE / 32;                 // 50000
  const int tpb = (tiles + NP2 - 1) / NP2;      // 49
  int t0 = blockIdx.x * tpb;
  int t1e = min(t0 + tpb, tiles);

  f32x4 acc[8][2];
#pragma unroll
  for (int m = 0; m < 8; ++m)
#pragma unroll
    for (int n = 0; n < 2; ++n) acc[m][n] = (f32x4){0.f, 0.f, 0.f, 0.f};

  Byte16 v0, v1;   // in-flight: 16B of rows 2rp, 2rp+1 (my half)
#define T2_LOAD(tt)                                                            \
  {                                                                            \
    int ebase = (tt) * 32;                                                     \
    int2 rr2 = *reinterpret_cast<const int2*>(eibase + ebase + 2 * rp);        \
    v0.v = *reinterpret_cast<const s16x8*>(Abf8 + (size_t)rr2.x * 128 + sg * 16); \
    v1.v = *reinterpret_cast<const s16x8*>(Abf8 + (size_t)rr2.y * 128 + sg * 16); \
  }

  if (t0 < t1e) T2_LOAD(t0);
  int cur = 0;
  for (int tt = t0; tt < t1e; ++tt) {
    unsigned char* buf = half ? Ts8[cur] : Td8[cur];
#pragma unroll
    for (int i = 0; i < 16; ++i) {
      int c = sg * 16 + i;
      *reinterpret_cast<ushort*>(buf + c * T8PAD + 2 * rp) =
          (ushort)v0.b[i] | ((ushort)v1.b[i] << 8);
    }
    if (tt + 1 < t1e) T2_LOAD(tt + 1);
    __syncthreads();   // buf[cur] ready (readers of buf[cur]@tt-2 done before prev barrier)
    long bh[2];
#pragma unroll
    for (int n = 0; n < 2; ++n)
      bh[n] = *reinterpret_cast<const long*>(
          &Ts8[cur][(w * 32 + n * 16 + lc) * T8PAD + lg * 8]);
#pragma unroll
    for (int m = 0; m < 8; ++m) {
      long ah = *reinterpret_cast<const long*>(
          &Td8[cur][(m * 16 + lc) * T8PAD + lg * 8]);
#pragma unroll
      for (int n = 0; n < 2; ++n)
        acc[m][n] = __builtin_amdgcn_mfma_f32_16x16x32_fp8_fp8(ah, bh[n], acc[m][n], 0, 0, 0);
    }
    cur ^= 1;
  }
#undef T2_LOAD
  // C/D layout (dtype-independent, verified): col = lane&15, row = (lane>>4)*4 + reg
  float* out = PT2 + (size_t)blockIdx.x * 16384;
#pragma unroll
  for (int m = 0; m < 8; ++m)
#pragma unroll
    for (int n = 0; n < 2; ++n)
#pragma unroll
      for (int r = 0; r < 4; ++r) {
        int row = m * 16 + lg * 4 + r;
        int col = (2 * w + n) * 16 + lc;
        out[row * 128 + col] = acc[m][n][r];
      }
}

// ---------------- T1 partials: A^T @ raw via MFMA (R5 verbatim) ----------------
__global__ __launch_bounds__(256) void k_t1(
    const float* __restrict__ A,
    const int* __restrict__ lf, const int* __restrict__ nf,
    const float* __restrict__ lemb, const float* __restrict__ nemb,
    float* __restrict__ PT1) {
  int t = threadIdx.x;
  int w = t >> 6, l = t & 63;
  int lg = l >> 4, lc = l & 15;
  const int tiles = ROADN / 32;                 // 6250
  const int tpb = (tiles + NP1 - 1) / NP1;      // 13
  int t0 = blockIdx.x * tpb;
  int t1e = min(t0 + tpb, tiles);

  f32x4 acc[8][2];
#pragma unroll
  for (int m = 0; m < 8; ++m)
#pragma unroll
    for (int n = 0; n < 2; ++n) acc[m][n] = (f32x4){0.f, 0.f, 0.f, 0.f};

  const int* idxp = (w == 0) ? lf : nf;

  for (int tt = t0; tt < t1e; ++tt) {
    int roff = tt * 32 + lg * 8;
    int4 i0 = *reinterpret_cast<const int4*>(idxp + roff);
    int4 i1 = *reinterpret_cast<const int4*>(idxp + roff + 4);
    int iv[8] = {i0.x, i0.y, i0.z, i0.w, i1.x, i1.y, i1.z, i1.w};
    const float* ap[8];
    const float* bp[8];
#pragma unroll
    for (int e = 0; e < 8; ++e) {
      ap[e] = A + (size_t)(roff + e) * 128 + lc;
      bp[e] = (w == 0) ? (lemb + (size_t)iv[e] * 32 + lc)
                       : (nemb + (size_t)iv[e] * 96 + (w * 32 - 32) + lc);
    }
    s16x8 bhi[2], blo[2];
#pragma unroll
    for (int n = 0; n < 2; ++n) {
      float bv[8];
#pragma unroll
      for (int e = 0; e < 8; ++e) bv[e] = bp[e][n * 16];
      cvt_split8(bv, bhi[n], blo[n]);
    }
#pragma unroll
    for (int m = 0; m < 8; ++m) {
      float av[8];
#pragma unroll
      for (int e = 0; e < 8; ++e) av[e] = ap[e][m * 16];
      s16x8 ahi, alo;
      cvt_split8(av, ahi, alo);
#pragma unroll
      for (int n = 0; n < 2; ++n) {
        acc[m][n] = __builtin_amdgcn_mfma_f32_16x16x32_bf16(ahi, bhi[n], acc[m][n], 0, 0, 0);
        acc[m][n] = __builtin_amdgcn_mfma_f32_16x16x32_bf16(ahi, blo[n], acc[m][n], 0, 0, 0);
        acc[m][n] = __builtin_amdgcn_mfma_f32_16x16x32_bf16(alo, bhi[n], acc[m][n], 0, 0, 0);
      }
    }
  }
  float* out = PT1 + (size_t)blockIdx.x * 16384;
#pragma unroll
  for (int m = 0; m < 8; ++m)
#pragma unroll
    for (int n = 0; n < 2; ++n)
#pragma unroll
      for (int r = 0; r < 4; ++r) {
        int row = m * 16 + lg * 4 + r;
        int col = (2 * w + n) * 16 + lc;
        out[row * 128 + col] = acc[m][n][r];
      }
}

// ---------------- reduce partials -> T1, T2 (p-split, high occupancy) --------
__global__ __launch_bounds__(256) void k_reduce(const float* __restrict__ PT1,
                                                const float* __restrict__ PT2,
                                                float* __restrict__ T1,
                                                float* __restrict__ T2) {
  int b = blockIdx.x;
  int which = b & 1;
  int echunk = (b >> 1) & 63;
  int pchunk = b >> 7;                        // 0..PSPLIT-1
  const float* P = which ? PT2 : PT1;
  int np = which ? NP2 : NP1;
  int ppc = np / PSPLIT;
  int e = echunk * 256 + threadIdx.x;
  const float* base = P + (size_t)pchunk * ppc * 16384 + e;
  float s = 0.f;
  for (int p = 0; p < ppc; ++p)
    s += base[(size_t)p * 16384];
  atomicAdd((which ? T2 : T1) + e, s);
}

// ---------------- all tiny 128x128 ops -> W12 [128,100] ----------------
#define ACC4(crow, lv, r4) \
  crow[0] += (lv) * (r4).x; crow[1] += (lv) * (r4).y; \
  crow[2] += (lv) * (r4).z; crow[3] += (lv) * (r4).w;

__global__ __launch_bounds__(1024) void k_small(
    const float* __restrict__ T1, const float* __restrict__ T2,
    const float* __restrict__ cs, const float* __restrict__ gcn_w,
    const float* __restrict__ gcn_b, const float* __restrict__ lin_w,
    float* __restrict__ Gg, float* __restrict__ FEg,
    float* __restrict__ W12) {
  __shared__ float SE[128 * 128];
  __shared__ float FA[128 * 128];
  __shared__ float sc[128];
  int t = threadIdx.x;
  int ty = t >> 5, tx = t & 31;
  if (t < 128) {
    float s = cs[t] - 1.f;
    sc[t] = 1.f / (fmaxf(s, 0.f) + 1.f);
  }
  __syncthreads();
  for (int idx = t; idx < 16384; idx += 1024)
    SE[idx] = sc[idx >> 7] * T1[idx];
  __syncthreads();
  // Gg = D * (SE @ gcn_w)
  {
    float c0[4] = {0,0,0,0}, c1[4] = {0,0,0,0}, c2[4] = {0,0,0,0}, c3[4] = {0,0,0,0};
    for (int m = 0; m < 128; ++m) {
      float4 r = *reinterpret_cast<const float4*>(gcn_w + m * 128 + tx * 4);
      float l0 = SE[(ty * 4 + 0) * 128 + m];
      float l1 = SE[(ty * 4 + 1) * 128 + m];
      float l2 = SE[(ty * 4 + 2) * 128 + m];
      float l3 = SE[(ty * 4 + 3) * 128 + m];
      ACC4(c0, l0, r); ACC4(c1, l1, r); ACC4(c2, l2, r); ACC4(c3, l3, r);
    }
    float* cr[4] = {c0, c1, c2, c3};
#pragma unroll
    for (int a = 0; a < 4; ++a) {
      int i = ty * 4 + a;
      float4 o = make_float4(sc[i]*cr[a][0], sc[i]*cr[a][1], sc[i]*cr[a][2], sc[i]*cr[a][3]);
      *reinterpret_cast<float4*>(Gg + i * 128 + tx * 4) = o;
    }
  }
  __syncthreads();
  // FA = H = D*(T2 @ Gg) + gcn_b
  {
    float c0[4] = {0,0,0,0}, c1[4] = {0,0,0,0}, c2[4] = {0,0,0,0}, c3[4] = {0,0,0,0};
    for (int m = 0; m < 128; ++m) {
      float4 r = *reinterpret_cast<const float4*>(Gg + m * 128 + tx * 4);
      float l0 = T2[(ty * 4 + 0) * 128 + m];
      float l1 = T2[(ty * 4 + 1) * 128 + m];
      float l2 = T2[(ty * 4 + 2) * 128 + m];
      float l3 = T2[(ty * 4 + 3) * 128 + m];
      ACC4(c0, l0, r); ACC4(c1, l1, r); ACC4(c2, l2, r); ACC4(c3, l3, r);
    }
    float4 b4 = *reinterpret_cast<const float4*>(gcn_b + tx * 4);
    float* cr[4] = {c0, c1, c2, c3};
#pragma unroll
    for (int a = 0; a < 4; ++a) {
      int i = ty * 4 + a;
      FA[i * 128 + tx * 4 + 0] = sc[i] * cr[a][0] + b4.x;
      FA[i * 128 + tx * 4 + 1] = sc[i] * cr[a][1] + b4.y;
      FA[i * 128 + tx * 4 + 2] = sc[i] * cr[a][2] + b4.z;
      FA[i * 128 + tx * 4 + 3] = sc[i] * cr[a][3] + b4.w;
    }
  }
  __syncthreads();
  if (t < 128) {
    int j = t;
    float mx = -3.4e38f;
    for (int i = 0; i < 128; ++i) mx = fmaxf(mx, FA[i * 128 + j]);
    float sum = 0.f;
    for (int i = 0; i < 128; ++i) {
      float e = expf(FA[i * 128 + j] - mx);
      FA[i * 128 + j] = e;
      sum += e;
    }
    float inv = 1.f / sum;
    for (int i = 0; i < 128; ++i) FA[i * 128 + j] *= inv;
  }
  __syncthreads();
  // FEg = FA^T @ SE
  {
    float c0[4] = {0,0,0,0}, c1[4] = {0,0,0,0}, c2[4] = {0,0,0,0}, c3[4] = {0,0,0,0};
    for (int m = 0; m < 128; ++m) {
      float4 r = *reinterpret_cast<const float4*>(&SE[m * 128 + tx * 4]);
      float l0 = FA[m * 128 + ty * 4 + 0];
      float l1 = FA[m * 128 + ty * 4 + 1];
      float l2 = FA[m * 128 + ty * 4 + 2];
      float l3 = FA[m * 128 + ty * 4 + 3];
      ACC4(c0, l0, r); ACC4(c1, l1, r); ACC4(c2, l2, r); ACC4(c3, l3, r);
    }
    float* cr[4] = {c0, c1, c2, c3};
#pragma unroll
    for (int a = 0; a < 4; ++a) {
      float4 o = make_float4(cr[a][0], cr[a][1], cr[a][2], cr[a][3]);
      *reinterpret_cast<float4*>(FEg + (ty * 4 + a) * 128 + tx * 4) = o;
    }
  }
  __syncthreads();
  // FF = FA @ FEg  (then FA <- FF)
  {
    float c0[4] = {0,0,0,0}, c1[4] = {0,0,0,0}, c2[4] = {0,0,0,0}, c3[4] = {0,0,0,0};
    for (int m = 0; m < 128; ++m) {
      float4 r = *reinterpret_cast<const float4*>(FEg + m * 128 + tx * 4);
      float l0 = FA[(ty * 4 + 0) * 128 + m];
      float l1 = FA[(ty * 4 + 1) * 128 + m];
      float l2 = FA[(ty * 4 + 2) * 128 + m];
      float l3 = FA[(ty * 4 + 3) * 128 + m];
      ACC4(c0, l0, r); ACC4(c1, l1, r); ACC4(c2, l2, r); ACC4(c3, l3, r);
    }
    __syncthreads();
    float* cr[4] = {c0, c1, c2, c3};
#pragma unroll
    for (int a = 0; a < 4; ++a) {
      int i = ty * 4 + a;
      FA[i * 128 + tx * 4 + 0] = cr[a][0];
      FA[i * 128 + tx * 4 + 1] = cr[a][1];
      FA[i * 128 + tx * 4 + 2] = cr[a][2];
      FA[i * 128 + tx * 4 + 3] = cr[a][3];
    }
  }
  __syncthreads();
  // W12[k][c] = sc[k] * sum_j (SE[k][j]*lin_w[128+j][c] + FA[k][j]*lin_w[256+j][c])
  if (tx < 25) {
    float c0[4] = {0,0,0,0}, c1[4] = {0,0,0,0}, c2[4] = {0,0,0,0}, c3[4] = {0,0,0,0};
    for (int j = 0; j < 128; ++j) {
      float4 r1 = *reinterpret_cast<const float4*>(lin_w + (128 + j) * 100 + tx * 4);
      float4 r2 = *reinterpret_cast<const float4*>(lin_w + (256 + j) * 100 + tx * 4);
      float s0 = SE[(ty * 4 + 0) * 128 + j], f0 = FA[(ty * 4 + 0) * 128 + j];
      float s1 = SE[(ty * 4 + 1) * 128 + j], f1 = FA[(ty * 4 + 1) * 128 + j];
      float s2 = SE[(ty * 4 + 2) * 128 + j], f2 = FA[(ty * 4 + 2) * 128 + j];
      float s3 = SE[(ty * 4 + 3) * 128 + j], f3 = FA[(ty * 4 + 3) * 128 + j];
      ACC4(c0, s0, r1); ACC4(c0, f0, r2);
      ACC4(c1, s1, r1); ACC4(c1, f1, r2);
      ACC4(c2, s2, r1); ACC4(c2, f2, r2);
      ACC4(c3, s3, r1); ACC4(c3, f3, r2);
    }
    float* cr[4] = {c0, c1, c2, c3};
#pragma unroll
    for (int a = 0; a < 4; ++a) {
      int k = ty * 4 + a;
#pragma unroll
      for (int b = 0; b < 4; ++b)
        W12[k * 100 + tx * 4 + b] = sc[k] * cr[a][b];
    }
  }
}

// ---------------- WThi/WTlo[col][k] bf16: padded transpose of [W0; W12] -----
__global__ __launch_bounds__(256) void k_wt(const float* __restrict__ lin_w,
                                            const float* __restrict__ W12,
                                            ushort* __restrict__ WThi,
                                            ushort* __restrict__ WTlo) {
  int idx = blockIdx.x * 256 + threadIdx.x;   // 0..28671
  if (idx >= 112 * 256) return;
  int col = idx >> 8;
  int k = idx & 255;
  float v = 0.f;
  if (col < 100)
    v = (k < 128) ? lin_w[k * 100 + col] : W12[(k - 128) * 100 + col];
  float z = 0.f;
  int h;
  asm("v_cvt_pk_bf16_f32 %0, %1, %2" : "=v"(h) : "v"(v), "v"(z));
  ushort hu = (ushort)(h & 0xFFFF);
  float hf = __builtin_bit_cast(float, (unsigned)hu << 16);
  float lof = v - hf;
  int lw2;
  asm("v_cvt_pk_bf16_f32 %0, %1, %2" : "=v"(lw2) : "v"(lof), "v"(z));
  WThi[idx] = hu;
  WTlo[idx] = (ushort)(lw2 & 0xFFFF);
}

// ---------------- X = in[200000,256] @ W[256,112pad] + b via MFMA ------------
// R14 structure + bf16 gather table Xbf[200000][128] for k_pred.
__global__ __launch_bounds__(1024, 4) void k_x(
    const float* __restrict__ A, const int* __restrict__ lf,
    const int* __restrict__ nf, const float* __restrict__ lemb,
    const float* __restrict__ nemb, const float* __restrict__ lin_b,
    const ushort* __restrict__ WThi, const ushort* __restrict__ WTlo,
    float* __restrict__ X, ushort* __restrict__ Xbf) {
  __shared__ ushort Whl[2][112 * WXPAD];
  int t = threadIdx.x;
  for (int i = t; i < 112 * 256; i += 1024) {
    int col = i >> 8;
    int k = i & 255;
    int d = col * WXPAD + k;
    Whl[0][d] = WThi[i];
    Whl[1][d] = WTlo[i];
  }
  __syncthreads();

  int wid = t >> 6, l = t & 63;
  int lg = l >> 4, lc = l & 15;
  int rb0 = blockIdx.x * 512 + wid * 32;     // this wave's 32 rows
  if (rb0 >= ROADN) return;                  // after the only barrier

  float bias[7];
#pragma unroll
  for (int n = 0; n < 7; ++n) {
    int c = n * 16 + lc;
    bias[n] = (c < 100) ? lin_b[c] : 0.f;
  }

  f32x4 acc[2][7];
#pragma unroll
  for (int m = 0; m < 2; ++m)
#pragma unroll
    for (int n = 0; n < 7; ++n) acc[m][n] = (f32x4){0.f, 0.f, 0.f, 0.f};

  int rr[2], lfv[2], nfv[2];
#pragma unroll
  for (int m = 0; m < 2; ++m) {
    int r = rb0 + m * 16 + lc;
    rr[m] = min(r, ROADN - 1);
    lfv[m] = lf[rr[m]];
    nfv[m] = nf[rr[m]];
  }

#pragma unroll
  for (int ks = 0; ks < 8; ++ks) {
    int kk = ks * 32;
    s16x8 ahi[2], alo[2];
#pragma unroll
    for (int m = 0; m < 2; ++m) {
      const float* p;
      if (ks == 0)
        p = lemb + (size_t)lfv[m] * 32 + lg * 8;
      else if (ks < 4)
        p = nemb + (size_t)nfv[m] * 96 + (kk - 32) + lg * 8;
      else
        p = A + (size_t)rr[m] * 128 + (kk - 128) + lg * 8;
      float4 u0 = *reinterpret_cast<const float4*>(p);
      float4 u1 = *reinterpret_cast<const float4*>(p + 4);
      float av[8] = {u0.x, u0.y, u0.z, u0.w, u1.x, u1.y, u1.z, u1.w};
      cvt_split8(av, ahi[m], alo[m]);
    }
#pragma unroll
    for (int n = 0; n < 7; ++n) {
      int off = (n * 16 + lc) * WXPAD + kk + lg * 8;
      s16x8 bh = *reinterpret_cast<const s16x8*>(&Whl[0][off]);
      s16x8 bl = *reinterpret_cast<const s16x8*>(&Whl[1][off]);
#pragma unroll
      for (int m = 0; m < 2; ++m) {
        acc[m][n] = __builtin_amdgcn_mfma_f32_16x16x32_bf16(ahi[m], bh, acc[m][n], 0, 0, 0);
        acc[m][n] = __builtin_amdgcn_mfma_f32_16x16x32_bf16(ahi[m], bl, acc[m][n], 0, 0, 0);
        acc[m][n] = __builtin_amdgcn_mfma_f32_16x16x32_bf16(alo[m], bh, acc[m][n], 0, 0, 0);
      }
    }
  }
  // store: C/D layout col = lane&15, row = (lane>>4)*4 + reg
#pragma unroll
  for (int m = 0; m < 2; ++m)
#pragma unroll
    for (int n = 0; n < 7; ++n) {
      int col = n * 16 + lc;
#pragma unroll
      for (int r4 = 0; r4 < 4; ++r4) {
        int row = rb0 + m * 16 + lg * 4 + r4;
        if (row < ROADN) {
          float v = acc[m][n][r4] + bias[n];
          if (col < 100) {
            X[(size_t)row * 100 + col] = v;
            Xbf[(size_t)row * 128 + col] = cvt1_bf16(v);
          } else {
            Xbf[(size_t)row * 128 + col] = 0;   // pad cols 100..111
          }
        }
      }
    }
}

// ---------------- pred[e] = dot(Xbf[se0[e]], Xbf[se1[e]]) (bf16 gathers) -----
__global__ __launch_bounds__(256) void k_pred(const ushort* __restrict__ Xbf,
                                              const int* __restrict__ se,
                                              float* __restrict__ out) {
  unsigned tid = blockIdx.x * 256u + threadIdx.x;
  unsigned e = tid >> 5, lane = tid & 31;
  int ra = se[e];
  int rb = se[NSEDGE + e];
  float acc = 0.f;
  if (lane < 28) {
    const ushort* xa = Xbf + (size_t)ra * 128 + lane * 4;
    const ushort* xb = Xbf + (size_t)rb * 128 + lane * 4;
    ushort4 a = *reinterpret_cast<const ushort4*>(xa);
    ushort4 b = *reinterpret_cast<const ushort4*>(xb);
    float ax = __builtin_bit_cast(float, (unsigned)a.x << 16);
    float ay = __builtin_bit_cast(float, (unsigned)a.y << 16);
    float az = __builtin_bit_cast(float, (unsigned)a.z << 16);
    float aw = __builtin_bit_cast(float, (unsigned)a.w << 16);
    float bx = __builtin_bit_cast(float, (unsigned)b.x << 16);
    float by = __builtin_bit_cast(float, (unsigned)b.y << 16);
    float bz = __builtin_bit_cast(float, (unsigned)b.z << 16);
    float bw = __builtin_bit_cast(float, (unsigned)b.w << 16);
    acc = ax * bx + ay * by + az * bz + aw * bw;
  }
#pragma unroll
  for (int off = 16; off > 0; off >>= 1)
    acc += __shfl_xor(acc, off, 32);
  if (lane == 0) out[e] = acc;
}

extern "C" void kernel_launch(void* const* d_in, const int* in_sizes, int n_in,
                              void* d_out, int out_size, void* d_ws, size_t ws_size,
                              hipStream_t stream) {
  const int*   lf   = (const int*)d_in[0];
  const int*   nf   = (const int*)d_in[1];
  const int*   ei   = (const int*)d_in[2];
  const float* A    = (const float*)d_in[3];
  const int*   se   = (const int*)d_in[4];
  const float* nemb = (const float*)d_in[5];
  const float* lemb = (const float*)d_in[6];
  const float* gw   = (const float*)d_in[7];
  const float* gb   = (const float*)d_in[8];
  const float* lw   = (const float*)d_in[9];
  const float* lb   = (const float*)d_in[10];

  float* ws  = (float*)d_ws;
  float* PT1 = ws;                           // 512*16384  = 8,388,608
  float* PT2 = PT1 + (size_t)NP1 * 16384;    // 1024*16384 = 16,777,216
  float* T1  = PT2 + (size_t)NP2 * 16384;    // 16,384
  float* T2  = T1 + 16384;                   // 16,384
  float* cs  = T2 + 16384;                   // 128
  float* Gg  = cs + 128;                     // 16,384
  float* FEg = Gg + 16384;                   // 16,384
  float* W12 = FEg + 16384;                  // 12,800
  ushort* WThi = (ushort*)(W12 + 12800);     // 28,672 ushorts (16B-aligned)
  ushort* WTlo = WThi + 112 * 256;           // 28,672 ushorts

  float* pred = (float*)d_out;
  float* X    = pred + NSEDGE;
  // Abf8 (25.6 MB fp8) lives in the X region of d_out (overwritten by k_x).
  unsigned char* Abf8 = (unsigned char*)X;
  // Xbf (51.2 MB bf16) lives in the PT1/PT2 region (dead after k_reduce).
  ushort* Xbf = (ushort*)PT1;

  // zero T1, T2, cs (contiguous; atomically accumulated)
  hipMemsetAsync(T1, 0, (size_t)(16384 * 2 + 128) * sizeof(float), stream);

  k_abf<<<2048, 256, 0, stream>>>(A, Abf8, cs);
  k_t1<<<NP1, 256, 0, stream>>>(A, lf, nf, lemb, nemb, PT1);
  k_t2<<<NP2, 256, 0, stream>>>(Abf8, ei, PT2);
  k_reduce<<<2 * 64 * PSPLIT, 256, 0, stream>>>(PT1, PT2, T1, T2);
  k_small<<<1, 1024, 0, stream>>>(T1, T2, cs, gw, gb, lw, Gg, FEg, W12);
  k_wt<<<112, 256, 0, stream>>>(lw, W12, WThi, WTlo);
  k_x<<<(ROADN + 511) / 512, 1024, 0, stream>>>(A, lf, nf, lemb, nemb, lb, WThi, WTlo, X, Xbf);
  k_pred<<<(NSEDGE * 32) / 256, 256, 0, stream>>>(Xbf, se, pred);
}

// Round 18
// 480.757 us; speedup vs baseline: 1.1628x; 1.0994x over previous
//
#include <hip/hip_runtime.h>
#include <cstdint>
#include <cstddef>

#define ROADN 200000
#define NEDGE 1600000
#define NSEDGE 1000000
#define NP1 512    // partial buffers for T1
#define NP2 1024   // partial buffers for T2
#define PSPLIT 16  // p-axis split for the partial reduce
#define T8PAD 40   // BYTES per transposed-LDS col (8B-aligned b64 reads, conflict-free)
#define WXPAD 264  // k_x LDS col stride in ushorts (132 dw == 4 mod 32 -> conflict-free b128)

typedef __attribute__((ext_vector_type(8))) short s16x8;
typedef __attribute__((ext_vector_type(4))) float f32x4;

union FragU { int i[4]; s16x8 s; };
union Byte16 { s16x8 v; unsigned char b[16]; };

// split 8 f32 -> bf16 hi + bf16 lo fragments. PROVEN R3/R5. v_cvt_pk low=src0
// (proven: R3/R5 hi/lo residuals would be O(1) garbage under a swap).
__device__ inline void cvt_split8(const float v[8], s16x8& hi, s16x8& lo) {
  FragU H, L;
  float lof[8];
#pragma unroll
  for (int p = 0; p < 4; ++p) {
    int h;
    asm("v_cvt_pk_bf16_f32 %0, %1, %2" : "=v"(h) : "v"(v[2 * p]), "v"(v[2 * p + 1]));
    H.i[p] = h;
    float h0 = __builtin_bit_cast(float, (unsigned)h << 16);
    float h1 = __builtin_bit_cast(float, (unsigned)h & 0xFFFF0000u);
    lof[2 * p] = v[2 * p] - h0;
    lof[2 * p + 1] = v[2 * p + 1] - h1;
  }
#pragma unroll
  for (int p = 0; p < 4; ++p) {
    int l;
    asm("v_cvt_pk_bf16_f32 %0, %1, %2" : "=v"(l) : "v"(lof[2 * p]), "v"(lof[2 * p + 1]));
    L.i[p] = l;
  }
  hi = H.s; lo = L.s;
}

// single f32 -> bf16 (rne, same rounding as cvt_pk's low slot)
__device__ inline ushort cvt1_bf16(float v) {
  float z = 0.f;
  int h;
  asm("v_cvt_pk_bf16_f32 %0, %1, %2" : "=v"(h) : "v"(v), "v"(z));
  return (ushort)(h & 0xFFFF);
}

// column normalization scale: 1 / (relu(colsum-1) + 1)
__device__ inline float sc_of(const float* cs, int i) {
  float s = cs[i] - 1.f;
  return 1.f / (fmaxf(s, 0.f) + 1.f);
}

// ---------------- fused: Abf8 = fp8_e4m3(A) + column sums of A ----------------
__global__ __launch_bounds__(256) void k_abf(const float* __restrict__ A,
                                             unsigned char* __restrict__ Abf8,
                                             float* __restrict__ cs) {
  __shared__ float csl[128];
  int t = threadIdx.x;
  if (t < 128) csl[t] = 0.f;
  __syncthreads();
  float ps[8] = {0.f, 0.f, 0.f, 0.f, 0.f, 0.f, 0.f, 0.f};
  const size_t ngroups = (size_t)ROADN * 128 / 8;   // 3,200,000
  for (size_t g = blockIdx.x * 256ull + threadIdx.x; g < ngroups;
       g += (size_t)gridDim.x * 256ull) {
    const float* p = A + g * 8;
    float4 u0 = *reinterpret_cast<const float4*>(p);
    float4 u1 = *reinterpret_cast<const float4*>(p + 4);
    float v[8] = {u0.x, u0.y, u0.z, u0.w, u1.x, u1.y, u1.z, u1.w};
#pragma unroll
    for (int j = 0; j < 8; ++j) ps[j] += v[j];
    int p0 = __builtin_amdgcn_cvt_pk_fp8_f32(v[0], v[1], 0, false);
    p0 = __builtin_amdgcn_cvt_pk_fp8_f32(v[2], v[3], p0, true);
    int p1 = __builtin_amdgcn_cvt_pk_fp8_f32(v[4], v[5], 0, false);
    p1 = __builtin_amdgcn_cvt_pk_fp8_f32(v[6], v[7], p1, true);
    int2 pk = make_int2(p0, p1);
    *reinterpret_cast<int2*>(Abf8 + g * 8) = pk;
  }
  int cb = (t * 8) & 127;
#pragma unroll
  for (int j = 0; j < 8; ++j)
    atomicAdd(&csl[cb + j], ps[j]);
  __syncthreads();
  if (t < 128) atomicAdd(&cs[t], csl[t]);
}

// ---------------- T2 partials: sum_e outer(A[dst_e], A[src_e]), fp8 ---------
__global__ __launch_bounds__(256, 4) void k_t2(const unsigned char* __restrict__ Abf8,
                                               const int* __restrict__ ei,
                                               float* __restrict__ PT2) {
  __shared__ unsigned char Td8[2][128 * T8PAD];
  __shared__ unsigned char Ts8[2][128 * T8PAD];
  int t = threadIdx.x;
  int w = t >> 6, l = t & 63;
  int lg = l >> 4, lc = l & 15;
  int half = t >> 7;          // 0: dst rows, 1: src rows
  int rp = t & 15;            // row-pair (rows 2rp, 2rp+1)
  int sg = (t >> 4) & 7;      // 16B segment (cols sg*16 .. sg*16+15)
  const int* eibase = ei + (size_t)half * NEDGE;
  const int tiles = NEDGE / 32;                 // 50000
  const int tpb = (tiles + NP2 - 1) / NP2;      // 49
  int t0 = blockIdx.x * tpb;
  int t1e = min(t0 + tpb, tiles);

  f32x4 acc[8][2];
#pragma unroll
  for (int m = 0; m < 8; ++m)
#pragma unroll
    for (int n = 0; n < 2; ++n) acc[m][n] = (f32x4){0.f, 0.f, 0.f, 0.f};

  Byte16 v0, v1;   // in-flight: 16B of rows 2rp, 2rp+1 (my half)
#define T2_LOAD(tt)                                                            \
  {                                                                            \
    int ebase = (tt) * 32;                                                     \
    int2 rr2 = *reinterpret_cast<const int2*>(eibase + ebase + 2 * rp);        \
    v0.v = *reinterpret_cast<const s16x8*>(Abf8 + (size_t)rr2.x * 128 + sg * 16); \
    v1.v = *reinterpret_cast<const s16x8*>(Abf8 + (size_t)rr2.y * 128 + sg * 16); \
  }

  if (t0 < t1e) T2_LOAD(t0);
  int cur = 0;
  for (int tt = t0; tt < t1e; ++tt) {
    unsigned char* buf = half ? Ts8[cur] : Td8[cur];
#pragma unroll
    for (int i = 0; i < 16; ++i) {
      int c = sg * 16 + i;
      *reinterpret_cast<ushort*>(buf + c * T8PAD + 2 * rp) =
          (ushort)v0.b[i] | ((ushort)v1.b[i] << 8);
    }
    if (tt + 1 < t1e) T2_LOAD(tt + 1);
    __syncthreads();
    long bh[2];
#pragma unroll
    for (int n = 0; n < 2; ++n)
      bh[n] = *reinterpret_cast<const long*>(
          &Ts8[cur][(w * 32 + n * 16 + lc) * T8PAD + lg * 8]);
#pragma unroll
    for (int m = 0; m < 8; ++m) {
      long ah = *reinterpret_cast<const long*>(
          &Td8[cur][(m * 16 + lc) * T8PAD + lg * 8]);
#pragma unroll
      for (int n = 0; n < 2; ++n)
        acc[m][n] = __builtin_amdgcn_mfma_f32_16x16x32_fp8_fp8(ah, bh[n], acc[m][n], 0, 0, 0);
    }
    cur ^= 1;
  }
#undef T2_LOAD
  float* out = PT2 + (size_t)blockIdx.x * 16384;
#pragma unroll
  for (int m = 0; m < 8; ++m)
#pragma unroll
    for (int n = 0; n < 2; ++n)
#pragma unroll
      for (int r = 0; r < 4; ++r) {
        int row = m * 16 + lg * 4 + r;
        int col = (2 * w + n) * 16 + lc;
        out[row * 128 + col] = acc[m][n][r];
      }
}

// ---------------- T1 partials: A^T @ raw via MFMA (R5 verbatim) ----------------
__global__ __launch_bounds__(256) void k_t1(
    const float* __restrict__ A,
    const int* __restrict__ lf, const int* __restrict__ nf,
    const float* __restrict__ lemb, const float* __restrict__ nemb,
    float* __restrict__ PT1) {
  int t = threadIdx.x;
  int w = t >> 6, l = t & 63;
  int lg = l >> 4, lc = l & 15;
  const int tiles = ROADN / 32;                 // 6250
  const int tpb = (tiles + NP1 - 1) / NP1;      // 13
  int t0 = blockIdx.x * tpb;
  int t1e = min(t0 + tpb, tiles);

  f32x4 acc[8][2];
#pragma unroll
  for (int m = 0; m < 8; ++m)
#pragma unroll
    for (int n = 0; n < 2; ++n) acc[m][n] = (f32x4){0.f, 0.f, 0.f, 0.f};

  const int* idxp = (w == 0) ? lf : nf;

  for (int tt = t0; tt < t1e; ++tt) {
    int roff = tt * 32 + lg * 8;
    int4 i0 = *reinterpret_cast<const int4*>(idxp + roff);
    int4 i1 = *reinterpret_cast<const int4*>(idxp + roff + 4);
    int iv[8] = {i0.x, i0.y, i0.z, i0.w, i1.x, i1.y, i1.z, i1.w};
    const float* ap[8];
    const float* bp[8];
#pragma unroll
    for (int e = 0; e < 8; ++e) {
      ap[e] = A + (size_t)(roff + e) * 128 + lc;
      bp[e] = (w == 0) ? (lemb + (size_t)iv[e] * 32 + lc)
                       : (nemb + (size_t)iv[e] * 96 + (w * 32 - 32) + lc);
    }
    s16x8 bhi[2], blo[2];
#pragma unroll
    for (int n = 0; n < 2; ++n) {
      float bv[8];
#pragma unroll
      for (int e = 0; e < 8; ++e) bv[e] = bp[e][n * 16];
      cvt_split8(bv, bhi[n], blo[n]);
    }
#pragma unroll
    for (int m = 0; m < 8; ++m) {
      float av[8];
#pragma unroll
      for (int e = 0; e < 8; ++e) av[e] = ap[e][m * 16];
      s16x8 ahi, alo;
      cvt_split8(av, ahi, alo);
#pragma unroll
      for (int n = 0; n < 2; ++n) {
        acc[m][n] = __builtin_amdgcn_mfma_f32_16x16x32_bf16(ahi, bhi[n], acc[m][n], 0, 0, 0);
        acc[m][n] = __builtin_amdgcn_mfma_f32_16x16x32_bf16(ahi, blo[n], acc[m][n], 0, 0, 0);
        acc[m][n] = __builtin_amdgcn_mfma_f32_16x16x32_bf16(alo, bhi[n], acc[m][n], 0, 0, 0);
      }
    }
  }
  float* out = PT1 + (size_t)blockIdx.x * 16384;
#pragma unroll
  for (int m = 0; m < 8; ++m)
#pragma unroll
    for (int n = 0; n < 2; ++n)
#pragma unroll
      for (int r = 0; r < 4; ++r) {
        int row = m * 16 + lg * 4 + r;
        int col = (2 * w + n) * 16 + lc;
        out[row * 128 + col] = acc[m][n][r];
      }
}

// ---------------- reduce partials -> T1, T2 (p-split, high occupancy) --------
__global__ __launch_bounds__(256) void k_reduce(const float* __restrict__ PT1,
                                                const float* __restrict__ PT2,
                                                float* __restrict__ T1,
                                                float* __restrict__ T2) {
  int b = blockIdx.x;
  int which = b & 1;
  int echunk = (b >> 1) & 63;
  int pchunk = b >> 7;                        // 0..PSPLIT-1
  const float* P = which ? PT2 : PT1;
  int np = which ? NP2 : NP1;
  int ppc = np / PSPLIT;
  int e = echunk * 256 + threadIdx.x;
  const float* base = P + (size_t)pchunk * ppc * 16384 + e;
  float s = 0.f;
  for (int p = 0; p < ppc; ++p)
    s += base[(size_t)p * 16384];
  atomicAdd((which ? T2 : T1) + e, s);
}

// ======= tiny 128x128 chain, parallelized across blocks (was k_small) =======
// SE = D*T1  (elementwise)
__global__ __launch_bounds__(256) void k_se(const float* __restrict__ T1,
                                            const float* __restrict__ cs,
                                            float* __restrict__ SE) {
  int idx = blockIdx.x * 256 + threadIdx.x;   // 0..16383
  if (idx >= 16384) return;
  SE[idx] = sc_of(cs, idx >> 7) * T1[idx];
}

// Gg = D*(SE @ gcn_w) : block = output row, thread = col (coalesced B reads)
__global__ __launch_bounds__(128) void k_mm1(const float* __restrict__ SE,
                                             const float* __restrict__ gw,
                                             const float* __restrict__ cs,
                                             float* __restrict__ Gg) {
  int b = blockIdx.x, j = threadIdx.x;
  const float* Lr = SE + b * 128;
  float acc = 0.f;
  for (int k = 0; k < 128; ++k)
    acc += Lr[k] * gw[k * 128 + j];
  Gg[b * 128 + j] = sc_of(cs, b) * acc;
}

// FA = D*(T2 @ Gg) + gcn_b
__global__ __launch_bounds__(128) void k_mm2(const float* __restrict__ T2,
                                             const float* __restrict__ Gg,
                                             const float* __restrict__ cs,
                                             const float* __restrict__ gb,
                                             float* __restrict__ FA) {
  int b = blockIdx.x, j = threadIdx.x;
  const float* Lr = T2 + b * 128;
  float acc = 0.f;
  for (int k = 0; k < 128; ++k)
    acc += Lr[k] * Gg[k * 128 + j];
  FA[b * 128 + j] = sc_of(cs, b) * acc + gb[j];
}

// column softmax in place: thread j owns column j (coalesced row reads)
__global__ __launch_bounds__(128) void k_soft(float* __restrict__ FA) {
  int j = threadIdx.x;
  float mx = -3.4e38f;
  for (int i = 0; i < 128; ++i) mx = fmaxf(mx, FA[i * 128 + j]);
  float sum = 0.f;
  for (int i = 0; i < 128; ++i) sum += expf(FA[i * 128 + j] - mx);
  float inv = 1.f / sum;
  for (int i = 0; i < 128; ++i)
    FA[i * 128 + j] = expf(FA[i * 128 + j] - mx) * inv;
}

// FEg = FA^T @ SE : C[i][j] = sum_k FA[k][i] * SE[k][j]
__global__ __launch_bounds__(128) void k_mm3(const float* __restrict__ FA,
                                             const float* __restrict__ SE,
                                             float* __restrict__ FEg) {
  int i = blockIdx.x, j = threadIdx.x;
  float acc = 0.f;
  for (int k = 0; k < 128; ++k)
    acc += FA[k * 128 + i] * SE[k * 128 + j];
  FEg[i * 128 + j] = acc;
}

// FF = FA @ FEg
__global__ __launch_bounds__(128) void k_mm4(const float* __restrict__ FA,
                                             const float* __restrict__ FEg,
                                             float* __restrict__ FF) {
  int b = blockIdx.x, j = threadIdx.x;
  const float* Lr = FA + b * 128;
  float acc = 0.f;
  for (int k = 0; k < 128; ++k)
    acc += Lr[k] * FEg[k * 128 + j];
  FF[b * 128 + j] = acc;
}

// W12[k][c] = sc[k] * sum_j (SE[k][j]*lin_w[128+j][c] + FF[k][j]*lin_w[256+j][c])
__global__ __launch_bounds__(128) void k_w12(const float* __restrict__ SE,
                                             const float* __restrict__ FF,
                                             const float* __restrict__ lin_w,
                                             const float* __restrict__ cs,
                                             float* __restrict__ W12) {
  int k = blockIdx.x, c = threadIdx.x;
  if (c >= 100) return;
  const float* Sr = SE + k * 128;
  const float* Fr = FF + k * 128;
  float acc = 0.f;
  for (int j = 0; j < 128; ++j)
    acc += Sr[j] * lin_w[(128 + j) * 100 + c] + Fr[j] * lin_w[(256 + j) * 100 + c];
  W12[k * 100 + c] = sc_of(cs, k) * acc;
}

// ---------------- WThi/WTlo[col][k] bf16: padded transpose of [W0; W12] -----
__global__ __launch_bounds__(256) void k_wt(const float* __restrict__ lin_w,
                                            const float* __restrict__ W12,
                                            ushort* __restrict__ WThi,
                                            ushort* __restrict__ WTlo) {
  int idx = blockIdx.x * 256 + threadIdx.x;   // 0..28671
  if (idx >= 112 * 256) return;
  int col = idx >> 8;
  int k = idx & 255;
  float v = 0.f;
  if (col < 100)
    v = (k < 128) ? lin_w[k * 100 + col] : W12[(k - 128) * 100 + col];
  float z = 0.f;
  int h;
  asm("v_cvt_pk_bf16_f32 %0, %1, %2" : "=v"(h) : "v"(v), "v"(z));
  ushort hu = (ushort)(h & 0xFFFF);
  float hf = __builtin_bit_cast(float, (unsigned)hu << 16);
  float lof = v - hf;
  int lw2;
  asm("v_cvt_pk_bf16_f32 %0, %1, %2" : "=v"(lw2) : "v"(lof), "v"(z));
  WThi[idx] = hu;
  WTlo[idx] = (ushort)(lw2 & 0xFFFF);
}

// ---------------- X = in[200000,256] @ W[256,112pad] + b via MFMA ------------
__global__ __launch_bounds__(1024, 4) void k_x(
    const float* __restrict__ A, const int* __restrict__ lf,
    const int* __restrict__ nf, const float* __restrict__ lemb,
    const float* __restrict__ nemb, const float* __restrict__ lin_b,
    const ushort* __restrict__ WThi, const ushort* __restrict__ WTlo,
    float* __restrict__ X, ushort* __restrict__ Xbf) {
  __shared__ ushort Whl[2][112 * WXPAD];
  int t = threadIdx.x;
  for (int i = t; i < 112 * 256; i += 1024) {
    int col = i >> 8;
    int k = i & 255;
    int d = col * WXPAD + k;
    Whl[0][d] = WThi[i];
    Whl[1][d] = WTlo[i];
  }
  __syncthreads();

  int wid = t >> 6, l = t & 63;
  int lg = l >> 4, lc = l & 15;
  int rb0 = blockIdx.x * 512 + wid * 32;     // this wave's 32 rows
  if (rb0 >= ROADN) return;                  // after the only barrier

  float bias[7];
#pragma unroll
  for (int n = 0; n < 7; ++n) {
    int c = n * 16 + lc;
    bias[n] = (c < 100) ? lin_b[c] : 0.f;
  }

  f32x4 acc[2][7];
#pragma unroll
  for (int m = 0; m < 2; ++m)
#pragma unroll
    for (int n = 0; n < 7; ++n) acc[m][n] = (f32x4){0.f, 0.f, 0.f, 0.f};

  int rr[2], lfv[2], nfv[2];
#pragma unroll
  for (int m = 0; m < 2; ++m) {
    int r = rb0 + m * 16 + lc;
    rr[m] = min(r, ROADN - 1);
    lfv[m] = lf[rr[m]];
    nfv[m] = nf[rr[m]];
  }

#pragma unroll
  for (int ks = 0; ks < 8; ++ks) {
    int kk = ks * 32;
    s16x8 ahi[2], alo[2];
#pragma unroll
    for (int m = 0; m < 2; ++m) {
      const float* p;
      if (ks == 0)
        p = lemb + (size_t)lfv[m] * 32 + lg * 8;
      else if (ks < 4)
        p = nemb + (size_t)nfv[m] * 96 + (kk - 32) + lg * 8;
      else
        p = A + (size_t)rr[m] * 128 + (kk - 128) + lg * 8;
      float4 u0 = *reinterpret_cast<const float4*>(p);
      float4 u1 = *reinterpret_cast<const float4*>(p + 4);
      float av[8] = {u0.x, u0.y, u0.z, u0.w, u1.x, u1.y, u1.z, u1.w};
      cvt_split8(av, ahi[m], alo[m]);
    }
#pragma unroll
    for (int n = 0; n < 7; ++n) {
      int off = (n * 16 + lc) * WXPAD + kk + lg * 8;
      s16x8 bh = *reinterpret_cast<const s16x8*>(&Whl[0][off]);
      s16x8 bl = *reinterpret_cast<const s16x8*>(&Whl[1][off]);
#pragma unroll
      for (int m = 0; m < 2; ++m) {
        acc[m][n] = __builtin_amdgcn_mfma_f32_16x16x32_bf16(ahi[m], bh, acc[m][n], 0, 0, 0);
        acc[m][n] = __builtin_amdgcn_mfma_f32_16x16x32_bf16(ahi[m], bl, acc[m][n], 0, 0, 0);
        acc[m][n] = __builtin_amdgcn_mfma_f32_16x16x32_bf16(alo[m], bh, acc[m][n], 0, 0, 0);
      }
    }
  }
  // store: C/D layout col = lane&15, row = (lane>>4)*4 + reg
#pragma unroll
  for (int m = 0; m < 2; ++m)
#pragma unroll
    for (int n = 0; n < 7; ++n) {
      int col = n * 16 + lc;
#pragma unroll
      for (int r4 = 0; r4 < 4; ++r4) {
        int row = rb0 + m * 16 + lg * 4 + r4;
        if (row < ROADN) {
          float v = acc[m][n][r4] + bias[n];
          if (col < 100) {
            X[(size_t)row * 100 + col] = v;
            Xbf[(size_t)row * 128 + col] = cvt1_bf16(v);
          } else {
            Xbf[(size_t)row * 128 + col] = 0;   // pad cols 100..111
          }
        }
      }
    }
}

// ---------------- pred[e] = dot(Xbf[se0[e]], Xbf[se1[e]]) (bf16 gathers) -----
__global__ __launch_bounds__(256) void k_pred(const ushort* __restrict__ Xbf,
                                              const int* __restrict__ se,
                                              float* __restrict__ out) {
  unsigned tid = blockIdx.x * 256u + threadIdx.x;
  unsigned e = tid >> 5, lane = tid & 31;
  int ra = se[e];
  int rb = se[NSEDGE + e];
  float acc = 0.f;
  if (lane < 28) {
    const ushort* xa = Xbf + (size_t)ra * 128 + lane * 4;
    const ushort* xb = Xbf + (size_t)rb * 128 + lane * 4;
    ushort4 a = *reinterpret_cast<const ushort4*>(xa);
    ushort4 b = *reinterpret_cast<const ushort4*>(xb);
    float ax = __builtin_bit_cast(float, (unsigned)a.x << 16);
    float ay = __builtin_bit_cast(float, (unsigned)a.y << 16);
    float az = __builtin_bit_cast(float, (unsigned)a.z << 16);
    float aw = __builtin_bit_cast(float, (unsigned)a.w << 16);
    float bx = __builtin_bit_cast(float, (unsigned)b.x << 16);
    float by = __builtin_bit_cast(float, (unsigned)b.y << 16);
    float bz = __builtin_bit_cast(float, (unsigned)b.z << 16);
    float bw = __builtin_bit_cast(float, (unsigned)b.w << 16);
    acc = ax * bx + ay * by + az * bz + aw * bw;
  }
#pragma unroll
  for (int off = 16; off > 0; off >>= 1)
    acc += __shfl_xor(acc, off, 32);
  if (lane == 0) out[e] = acc;
}

extern "C" void kernel_launch(void* const* d_in, const int* in_sizes, int n_in,
                              void* d_out, int out_size, void* d_ws, size_t ws_size,
                              hipStream_t stream) {
  const int*   lf   = (const int*)d_in[0];
  const int*   nf   = (const int*)d_in[1];
  const int*   ei   = (const int*)d_in[2];
  const float* A    = (const float*)d_in[3];
  const int*   se   = (const int*)d_in[4];
  const float* nemb = (const float*)d_in[5];
  const float* lemb = (const float*)d_in[6];
  const float* gw   = (const float*)d_in[7];
  const float* gb   = (const float*)d_in[8];
  const float* lw   = (const float*)d_in[9];
  const float* lb   = (const float*)d_in[10];

  float* ws  = (float*)d_ws;
  float* PT1 = ws;                           // 512*16384  = 8,388,608
  float* PT2 = PT1 + (size_t)NP1 * 16384;    // 1024*16384 = 16,777,216
  float* T1  = PT2 + (size_t)NP2 * 16384;    // 16,384
  float* T2  = T1 + 16384;                   // 16,384
  float* cs  = T2 + 16384;                   // 128
  float* Gg  = cs + 128;                     // 16,384
  float* FEg = Gg + 16384;                   // 16,384
  float* W12 = FEg + 16384;                  // 12,800
  ushort* WThi = (ushort*)(W12 + 12800);     // 28,672 ushorts (16B-aligned)
  ushort* WTlo = WThi + 112 * 256;           // 28,672 ushorts
  float* SEb = (float*)(WTlo + 112 * 256);   // 16,384
  float* FAb = SEb + 16384;                  // 16,384
  float* FFb = FAb + 16384;                  // 16,384

  float* pred = (float*)d_out;
  float* X    = pred + NSEDGE;
  // Abf8 (25.6 MB fp8) lives in the X region of d_out (overwritten by k_x).
  unsigned char* Abf8 = (unsigned char*)X;
  // Xbf (51.2 MB bf16) lives in the PT1/PT2 region (dead after k_reduce).
  ushort* Xbf = (ushort*)PT1;

  // zero T1, T2, cs (contiguous; atomically accumulated)
  hipMemsetAsync(T1, 0, (size_t)(16384 * 2 + 128) * sizeof(float), stream);

  k_abf<<<2048, 256, 0, stream>>>(A, Abf8, cs);
  k_t1<<<NP1, 256, 0, stream>>>(A, lf, nf, lemb, nemb, PT1);
  k_t2<<<NP2, 256, 0, stream>>>(Abf8, ei, PT2);
  k_reduce<<<2 * 64 * PSPLIT, 256, 0, stream>>>(PT1, PT2, T1, T2);
  // tiny 128x128 chain, each stage parallel across blocks
  k_se<<<64, 256, 0, stream>>>(T1, cs, SEb);
  k_mm1<<<128, 128, 0, stream>>>(SEb, gw, cs, Gg);
  k_mm2<<<128, 128, 0, stream>>>(T2, Gg, cs, gb, FAb);
  k_soft<<<1, 128, 0, stream>>>(FAb);
  k_mm3<<<128, 128, 0, stream>>>(FAb, SEb, FEg);
  k_mm4<<<128, 128, 0, stream>>>(FAb, FEg, FFb);
  k_w12<<<128, 128, 0, stream>>>(SEb, FFb, lw, cs, W12);
  k_wt<<<112, 256, 0, stream>>>(lw, W12, WThi, WTlo);
  k_x<<<(ROADN + 511) / 512, 1024, 0, stream>>>(A, lf, nf, lemb, nemb, lb, WThi, WTlo, X, Xbf);
  k_pred<<<(NSEDGE * 32) / 256, 256, 0, stream>>>(Xbf, se, pred);
}

// Round 19
// 452.913 us; speedup vs baseline: 1.2343x; 1.0615x over previous
//
#include <hip/hip_runtime.h>
#include <cstdint>
#include <cstddef>

#define ROADN 200000
#define NEDGE 1600000
#define NSEDGE 1000000
#define NP1 512    // partial buffers for T1
#define NP2 1024   // partial buffers for T2
#define PSPLIT 16  // p-axis split for the partial reduce
#define T8PAD 40   // BYTES per transposed-LDS col (8B-aligned b64 reads, conflict-free)
#define WXPAD 264  // k_x LDS col stride in ushorts (132 dw == 4 mod 32 -> conflict-free b128)

typedef __attribute__((ext_vector_type(8))) short s16x8;
typedef __attribute__((ext_vector_type(4))) float f32x4;

union FragU { int i[4]; s16x8 s; };
union Byte16 { s16x8 v; unsigned char b[16]; };

// split 8 f32 -> bf16 hi + bf16 lo fragments. PROVEN R3/R5. v_cvt_pk low=src0
// (proven: R3/R5 hi/lo residuals would be O(1) garbage under a swap).
__device__ inline void cvt_split8(const float v[8], s16x8& hi, s16x8& lo) {
  FragU H, L;
  float lof[8];
#pragma unroll
  for (int p = 0; p < 4; ++p) {
    int h;
    asm("v_cvt_pk_bf16_f32 %0, %1, %2" : "=v"(h) : "v"(v[2 * p]), "v"(v[2 * p + 1]));
    H.i[p] = h;
    float h0 = __builtin_bit_cast(float, (unsigned)h << 16);
    float h1 = __builtin_bit_cast(float, (unsigned)h & 0xFFFF0000u);
    lof[2 * p] = v[2 * p] - h0;
    lof[2 * p + 1] = v[2 * p + 1] - h1;
  }
#pragma unroll
  for (int p = 0; p < 4; ++p) {
    int l;
    asm("v_cvt_pk_bf16_f32 %0, %1, %2" : "=v"(l) : "v"(lof[2 * p]), "v"(lof[2 * p + 1]));
    L.i[p] = l;
  }
  hi = H.s; lo = L.s;
}

// single f32 -> bf16 (rne, same rounding as cvt_pk's low slot)
__device__ inline ushort cvt1_bf16(float v) {
  float z = 0.f;
  int h;
  asm("v_cvt_pk_bf16_f32 %0, %1, %2" : "=v"(h) : "v"(v), "v"(z));
  return (ushort)(h & 0xFFFF);
}

// column normalization scale: 1 / (relu(colsum-1) + 1)
__device__ inline float sc_of(const float* cs, int i) {
  float s = cs[i] - 1.f;
  return 1.f / (fmaxf(s, 0.f) + 1.f);
}

// ---------------- fused: Abf8 = fp8_e4m3(A) + column sums of A ----------------
__global__ __launch_bounds__(256) void k_abf(const float* __restrict__ A,
                                             unsigned char* __restrict__ Abf8,
                                             float* __restrict__ cs) {
  __shared__ float csl[128];
  int t = threadIdx.x;
  if (t < 128) csl[t] = 0.f;
  __syncthreads();
  float ps[8] = {0.f, 0.f, 0.f, 0.f, 0.f, 0.f, 0.f, 0.f};
  const size_t ngroups = (size_t)ROADN * 128 / 8;   // 3,200,000
  for (size_t g = blockIdx.x * 256ull + threadIdx.x; g < ngroups;
       g += (size_t)gridDim.x * 256ull) {
    const float* p = A + g * 8;
    float4 u0 = *reinterpret_cast<const float4*>(p);
    float4 u1 = *reinterpret_cast<const float4*>(p + 4);
    float v[8] = {u0.x, u0.y, u0.z, u0.w, u1.x, u1.y, u1.z, u1.w};
#pragma unroll
    for (int j = 0; j < 8; ++j) ps[j] += v[j];
    int p0 = __builtin_amdgcn_cvt_pk_fp8_f32(v[0], v[1], 0, false);
    p0 = __builtin_amdgcn_cvt_pk_fp8_f32(v[2], v[3], p0, true);
    int p1 = __builtin_amdgcn_cvt_pk_fp8_f32(v[4], v[5], 0, false);
    p1 = __builtin_amdgcn_cvt_pk_fp8_f32(v[6], v[7], p1, true);
    int2 pk = make_int2(p0, p1);
    *reinterpret_cast<int2*>(Abf8 + g * 8) = pk;
  }
  int cb = (t * 8) & 127;
#pragma unroll
  for (int j = 0; j < 8; ++j)
    atomicAdd(&csl[cb + j], ps[j]);
  __syncthreads();
  if (t < 128) atomicAdd(&cs[t], csl[t]);
}

// ---------------- T2 partials: sum_e outer(A[dst_e], A[src_e]), fp8 ---------
__global__ __launch_bounds__(256, 4) void k_t2(const unsigned char* __restrict__ Abf8,
                                               const int* __restrict__ ei,
                                               float* __restrict__ PT2) {
  __shared__ unsigned char Td8[2][128 * T8PAD];
  __shared__ unsigned char Ts8[2][128 * T8PAD];
  int t = threadIdx.x;
  int w = t >> 6, l = t & 63;
  int lg = l >> 4, lc = l & 15;
  int half = t >> 7;          // 0: dst rows, 1: src rows
  int rp = t & 15;            // row-pair (rows 2rp, 2rp+1)
  int sg = (t >> 4) & 7;      // 16B segment (cols sg*16 .. sg*16+15)
  const int* eibase = ei + (size_t)half * NEDGE;
  const int tiles = NEDGE / 32;                 // 50000
  const int tpb = (tiles + NP2 - 1) / NP2;      // 49
  int t0 = blockIdx.x * tpb;
  int t1e = min(t0 + tpb, tiles);

  f32x4 acc[8][2];
#pragma unroll
  for (int m = 0; m < 8; ++m)
#pragma unroll
    for (int n = 0; n < 2; ++n) acc[m][n] = (f32x4){0.f, 0.f, 0.f, 0.f};

  Byte16 v0, v1;   // in-flight: 16B of rows 2rp, 2rp+1 (my half)
#define T2_LOAD(tt)                                                            \
  {                                                                            \
    int ebase = (tt) * 32;                                                     \
    int2 rr2 = *reinterpret_cast<const int2*>(eibase + ebase + 2 * rp);        \
    v0.v = *reinterpret_cast<const s16x8*>(Abf8 + (size_t)rr2.x * 128 + sg * 16); \
    v1.v = *reinterpret_cast<const s16x8*>(Abf8 + (size_t)rr2.y * 128 + sg * 16); \
  }

  if (t0 < t1e) T2_LOAD(t0);
  int cur = 0;
  for (int tt = t0; tt < t1e; ++tt) {
    unsigned char* buf = half ? Ts8[cur] : Td8[cur];
#pragma unroll
    for (int i = 0; i < 16; ++i) {
      int c = sg * 16 + i;
      *reinterpret_cast<ushort*>(buf + c * T8PAD + 2 * rp) =
          (ushort)v0.b[i] | ((ushort)v1.b[i] << 8);
    }
    if (tt + 1 < t1e) T2_LOAD(tt + 1);
    __syncthreads();
    long bh[2];
#pragma unroll
    for (int n = 0; n < 2; ++n)
      bh[n] = *reinterpret_cast<const long*>(
          &Ts8[cur][(w * 32 + n * 16 + lc) * T8PAD + lg * 8]);
#pragma unroll
    for (int m = 0; m < 8; ++m) {
      long ah = *reinterpret_cast<const long*>(
          &Td8[cur][(m * 16 + lc) * T8PAD + lg * 8]);
#pragma unroll
      for (int n = 0; n < 2; ++n)
        acc[m][n] = __builtin_amdgcn_mfma_f32_16x16x32_fp8_fp8(ah, bh[n], acc[m][n], 0, 0, 0);
    }
    cur ^= 1;
  }
#undef T2_LOAD
  float* out = PT2 + (size_t)blockIdx.x * 16384;
#pragma unroll
  for (int m = 0; m < 8; ++m)
#pragma unroll
    for (int n = 0; n < 2; ++n)
#pragma unroll
      for (int r = 0; r < 4; ++r) {
        int row = m * 16 + lg * 4 + r;
        int col = (2 * w + n) * 16 + lc;
        out[row * 128 + col] = acc[m][n][r];
      }
}

// ---------------- T1 partials: A^T @ raw via MFMA (R5 verbatim) ----------------
__global__ __launch_bounds__(256) void k_t1(
    const float* __restrict__ A,
    const int* __restrict__ lf, const int* __restrict__ nf,
    const float* __restrict__ lemb, const float* __restrict__ nemb,
    float* __restrict__ PT1) {
  int t = threadIdx.x;
  int w = t >> 6, l = t & 63;
  int lg = l >> 4, lc = l & 15;
  const int tiles = ROADN / 32;                 // 6250
  const int tpb = (tiles + NP1 - 1) / NP1;      // 13
  int t0 = blockIdx.x * tpb;
  int t1e = min(t0 + tpb, tiles);

  f32x4 acc[8][2];
#pragma unroll
  for (int m = 0; m < 8; ++m)
#pragma unroll
    for (int n = 0; n < 2; ++n) acc[m][n] = (f32x4){0.f, 0.f, 0.f, 0.f};

  const int* idxp = (w == 0) ? lf : nf;

  for (int tt = t0; tt < t1e; ++tt) {
    int roff = tt * 32 + lg * 8;
    int4 i0 = *reinterpret_cast<const int4*>(idxp + roff);
    int4 i1 = *reinterpret_cast<const int4*>(idxp + roff + 4);
    int iv[8] = {i0.x, i0.y, i0.z, i0.w, i1.x, i1.y, i1.z, i1.w};
    const float* ap[8];
    const float* bp[8];
#pragma unroll
    for (int e = 0; e < 8; ++e) {
      ap[e] = A + (size_t)(roff + e) * 128 + lc;
      bp[e] = (w == 0) ? (lemb + (size_t)iv[e] * 32 + lc)
                       : (nemb + (size_t)iv[e] * 96 + (w * 32 - 32) + lc);
    }
    s16x8 bhi[2], blo[2];
#pragma unroll
    for (int n = 0; n < 2; ++n) {
      float bv[8];
#pragma unroll
      for (int e = 0; e < 8; ++e) bv[e] = bp[e][n * 16];
      cvt_split8(bv, bhi[n], blo[n]);
    }
#pragma unroll
    for (int m = 0; m < 8; ++m) {
      float av[8];
#pragma unroll
      for (int e = 0; e < 8; ++e) av[e] = ap[e][m * 16];
      s16x8 ahi, alo;
      cvt_split8(av, ahi, alo);
#pragma unroll
      for (int n = 0; n < 2; ++n) {
        acc[m][n] = __builtin_amdgcn_mfma_f32_16x16x32_bf16(ahi, bhi[n], acc[m][n], 0, 0, 0);
        acc[m][n] = __builtin_amdgcn_mfma_f32_16x16x32_bf16(ahi, blo[n], acc[m][n], 0, 0, 0);
        acc[m][n] = __builtin_amdgcn_mfma_f32_16x16x32_bf16(alo, bhi[n], acc[m][n], 0, 0, 0);
      }
    }
  }
  float* out = PT1 + (size_t)blockIdx.x * 16384;
#pragma unroll
  for (int m = 0; m < 8; ++m)
#pragma unroll
    for (int n = 0; n < 2; ++n)
#pragma unroll
      for (int r = 0; r < 4; ++r) {
        int row = m * 16 + lg * 4 + r;
        int col = (2 * w + n) * 16 + lc;
        out[row * 128 + col] = acc[m][n][r];
      }
}

// ---------------- reduce partials -> T1, T2 (p-split, high occupancy) --------
__global__ __launch_bounds__(256) void k_reduce(const float* __restrict__ PT1,
                                                const float* __restrict__ PT2,
                                                float* __restrict__ T1,
                                                float* __restrict__ T2) {
  int b = blockIdx.x;
  int which = b & 1;
  int echunk = (b >> 1) & 63;
  int pchunk = b >> 7;                        // 0..PSPLIT-1
  const float* P = which ? PT2 : PT1;
  int np = which ? NP2 : NP1;
  int ppc = np / PSPLIT;
  int e = echunk * 256 + threadIdx.x;
  const float* base = P + (size_t)pchunk * ppc * 16384 + e;
  float s = 0.f;
  for (int p = 0; p < ppc; ++p)
    s += base[(size_t)p * 16384];
  atomicAdd((which ? T2 : T1) + e, s);
}

// ======= tiny 128x128 chain, parallelized across blocks =======
__global__ __launch_bounds__(256) void k_se(const float* __restrict__ T1,
                                            const float* __restrict__ cs,
                                            float* __restrict__ SE) {
  int idx = blockIdx.x * 256 + threadIdx.x;   // 0..16383
  if (idx >= 16384) return;
  SE[idx] = sc_of(cs, idx >> 7) * T1[idx];
}

__global__ __launch_bounds__(128) void k_mm1(const float* __restrict__ SE,
                                             const float* __restrict__ gw,
                                             const float* __restrict__ cs,
                                             float* __restrict__ Gg) {
  int b = blockIdx.x, j = threadIdx.x;
  const float* Lr = SE + b * 128;
  float acc = 0.f;
  for (int k = 0; k < 128; ++k)
    acc += Lr[k] * gw[k * 128 + j];
  Gg[b * 128 + j] = sc_of(cs, b) * acc;
}

__global__ __launch_bounds__(128) void k_mm2(const float* __restrict__ T2,
                                             const float* __restrict__ Gg,
                                             const float* __restrict__ cs,
                                             const float* __restrict__ gb,
                                             float* __restrict__ FA) {
  int b = blockIdx.x, j = threadIdx.x;
  const float* Lr = T2 + b * 128;
  float acc = 0.f;
  for (int k = 0; k < 128; ++k)
    acc += Lr[k] * Gg[k * 128 + j];
  FA[b * 128 + j] = sc_of(cs, b) * acc + gb[j];
}

__global__ __launch_bounds__(128) void k_soft(float* __restrict__ FA) {
  int j = threadIdx.x;
  float mx = -3.4e38f;
  for (int i = 0; i < 128; ++i) mx = fmaxf(mx, FA[i * 128 + j]);
  float sum = 0.f;
  for (int i = 0; i < 128; ++i) sum += expf(FA[i * 128 + j] - mx);
  float inv = 1.f / sum;
  for (int i = 0; i < 128; ++i)
    FA[i * 128 + j] = expf(FA[i * 128 + j] - mx) * inv;
}

__global__ __launch_bounds__(128) void k_mm3(const float* __restrict__ FA,
                                             const float* __restrict__ SE,
                                             float* __restrict__ FEg) {
  int i = blockIdx.x, j = threadIdx.x;
  float acc = 0.f;
  for (int k = 0; k < 128; ++k)
    acc += FA[k * 128 + i] * SE[k * 128 + j];
  FEg[i * 128 + j] = acc;
}

__global__ __launch_bounds__(128) void k_mm4(const float* __restrict__ FA,
                                             const float* __restrict__ FEg,
                                             float* __restrict__ FF) {
  int b = blockIdx.x, j = threadIdx.x;
  const float* Lr = FA + b * 128;
  float acc = 0.f;
  for (int k = 0; k < 128; ++k)
    acc += Lr[k] * FEg[k * 128 + j];
  FF[b * 128 + j] = acc;
}

__global__ __launch_bounds__(128) void k_w12(const float* __restrict__ SE,
                                             const float* __restrict__ FF,
                                             const float* __restrict__ lin_w,
                                             const float* __restrict__ cs,
                                             float* __restrict__ W12) {
  int k = blockIdx.x, c = threadIdx.x;
  if (c >= 100) return;
  const float* Sr = SE + k * 128;
  const float* Fr = FF + k * 128;
  float acc = 0.f;
  for (int j = 0; j < 128; ++j)
    acc += Sr[j] * lin_w[(128 + j) * 100 + c] + Fr[j] * lin_w[(256 + j) * 100 + c];
  W12[k * 100 + c] = sc_of(cs, k) * acc;
}

// ---------------- WThi/WTlo[col][k] bf16: padded transpose of [W0; W12] -----
__global__ __launch_bounds__(256) void k_wt(const float* __restrict__ lin_w,
                                            const float* __restrict__ W12,
                                            ushort* __restrict__ WThi,
                                            ushort* __restrict__ WTlo) {
  int idx = blockIdx.x * 256 + threadIdx.x;   // 0..28671
  if (idx >= 112 * 256) return;
  int col = idx >> 8;
  int k = idx & 255;
  float v = 0.f;
  if (col < 100)
    v = (k < 128) ? lin_w[k * 100 + col] : W12[(k - 128) * 100 + col];
  float z = 0.f;
  int h;
  asm("v_cvt_pk_bf16_f32 %0, %1, %2" : "=v"(h) : "v"(v), "v"(z));
  ushort hu = (ushort)(h & 0xFFFF);
  float hf = __builtin_bit_cast(float, (unsigned)hu << 16);
  float lof = v - hf;
  int lw2;
  asm("v_cvt_pk_bf16_f32 %0, %1, %2" : "=v"(lw2) : "v"(lof), "v"(z));
  WThi[idx] = hu;
  WTlo[idx] = (ushort)(lw2 & 0xFFFF);
}

// ---------------- X = in[200000,256] @ W[256,112pad] + b via MFMA ------------
__global__ __launch_bounds__(1024, 4) void k_x(
    const float* __restrict__ A, const int* __restrict__ lf,
    const int* __restrict__ nf, const float* __restrict__ lemb,
    const float* __restrict__ nemb, const float* __restrict__ lin_b,
    const ushort* __restrict__ WThi, const ushort* __restrict__ WTlo,
    float* __restrict__ X, ushort* __restrict__ Xbf) {
  __shared__ ushort Whl[2][112 * WXPAD];
  int t = threadIdx.x;
  for (int i = t; i < 112 * 256; i += 1024) {
    int col = i >> 8;
    int k = i & 255;
    int d = col * WXPAD + k;
    Whl[0][d] = WThi[i];
    Whl[1][d] = WTlo[i];
  }
  __syncthreads();

  int wid = t >> 6, l = t & 63;
  int lg = l >> 4, lc = l & 15;
  int rb0 = blockIdx.x * 512 + wid * 32;     // this wave's 32 rows
  if (rb0 >= ROADN) return;                  // after the only barrier

  float bias[7];
#pragma unroll
  for (int n = 0; n < 7; ++n) {
    int c = n * 16 + lc;
    bias[n] = (c < 100) ? lin_b[c] : 0.f;
  }

  f32x4 acc[2][7];
#pragma unroll
  for (int m = 0; m < 2; ++m)
#pragma unroll
    for (int n = 0; n < 7; ++n) acc[m][n] = (f32x4){0.f, 0.f, 0.f, 0.f};

  int rr[2], lfv[2], nfv[2];
#pragma unroll
  for (int m = 0; m < 2; ++m) {
    int r = rb0 + m * 16 + lc;
    rr[m] = min(r, ROADN - 1);
    lfv[m] = lf[rr[m]];
    nfv[m] = nf[rr[m]];
  }

#pragma unroll
  for (int ks = 0; ks < 8; ++ks) {
    int kk = ks * 32;
    s16x8 ahi[2], alo[2];
#pragma unroll
    for (int m = 0; m < 2; ++m) {
      const float* p;
      if (ks == 0)
        p = lemb + (size_t)lfv[m] * 32 + lg * 8;
      else if (ks < 4)
        p = nemb + (size_t)nfv[m] * 96 + (kk - 32) + lg * 8;
      else
        p = A + (size_t)rr[m] * 128 + (kk - 128) + lg * 8;
      float4 u0 = *reinterpret_cast<const float4*>(p);
      float4 u1 = *reinterpret_cast<const float4*>(p + 4);
      float av[8] = {u0.x, u0.y, u0.z, u0.w, u1.x, u1.y, u1.z, u1.w};
      cvt_split8(av, ahi[m], alo[m]);
    }
#pragma unroll
    for (int n = 0; n < 7; ++n) {
      int off = (n * 16 + lc) * WXPAD + kk + lg * 8;
      s16x8 bh = *reinterpret_cast<const s16x8*>(&Whl[0][off]);
      s16x8 bl = *reinterpret_cast<const s16x8*>(&Whl[1][off]);
#pragma unroll
      for (int m = 0; m < 2; ++m) {
        acc[m][n] = __builtin_amdgcn_mfma_f32_16x16x32_bf16(ahi[m], bh, acc[m][n], 0, 0, 0);
        acc[m][n] = __builtin_amdgcn_mfma_f32_16x16x32_bf16(ahi[m], bl, acc[m][n], 0, 0, 0);
        acc[m][n] = __builtin_amdgcn_mfma_f32_16x16x32_bf16(alo[m], bh, acc[m][n], 0, 0, 0);
      }
    }
  }
  // store: C/D layout col = lane&15, row = (lane>>4)*4 + reg
#pragma unroll
  for (int m = 0; m < 2; ++m)
#pragma unroll
    for (int n = 0; n < 7; ++n) {
      int col = n * 16 + lc;
#pragma unroll
      for (int r4 = 0; r4 < 4; ++r4) {
        int row = rb0 + m * 16 + lg * 4 + r4;
        if (row < ROADN) {
          float v = acc[m][n][r4] + bias[n];
          if (col < 100) {
            X[(size_t)row * 100 + col] = v;
            Xbf[(size_t)row * 128 + col] = cvt1_bf16(v);
          } else {
            Xbf[(size_t)row * 128 + col] = 0;   // pad cols 100..111
          }
        }
      }
    }
}

// ---------------- pred[e] = dot(Xbf[se0[e]], Xbf[se1[e]]) -------------------
// 16 lanes per edge: lane l (<14) reads ushort8 covering elements 8l..8l+7 of
// each 112-padded row (cols 100-111 zero), 8 cvt+fma, 4-step 16-wide reduce.
// Halves wave count and load instructions vs the 32-lane version; same lines.
__global__ __launch_bounds__(256) void k_pred(const ushort* __restrict__ Xbf,
                                              const int* __restrict__ se,
                                              float* __restrict__ out) {
  unsigned tid = blockIdx.x * 256u + threadIdx.x;
  unsigned e = tid >> 4;          // 16 lanes per edge
  unsigned lane = tid & 15;
  int ra = se[e];
  int rb = se[NSEDGE + e];
  float acc = 0.f;
  if (lane < 14) {
    const ushort* xa = Xbf + (size_t)ra * 128 + lane * 8;
    const ushort* xb = Xbf + (size_t)rb * 128 + lane * 8;
    s16x8 a = *reinterpret_cast<const s16x8*>(xa);
    s16x8 b = *reinterpret_cast<const s16x8*>(xb);
#pragma unroll
    for (int j = 0; j < 8; ++j) {
      float av = __builtin_bit_cast(float, ((unsigned)(ushort)a[j]) << 16);
      float bv = __builtin_bit_cast(float, ((unsigned)(ushort)b[j]) << 16);
      acc += av * bv;
    }
  }
  acc += __shfl_xor(acc, 8);
  acc += __shfl_xor(acc, 4);
  acc += __shfl_xor(acc, 2);
  acc += __shfl_xor(acc, 1);
  if (lane == 0) out[e] = acc;
}

extern "C" void kernel_launch(void* const* d_in, const int* in_sizes, int n_in,
                              void* d_out, int out_size, void* d_ws, size_t ws_size,
                              hipStream_t stream) {
  const int*   lf   = (const int*)d_in[0];
  const int*   nf   = (const int*)d_in[1];
  const int*   ei   = (const int*)d_in[2];
  const float* A    = (const float*)d_in[3];
  const int*   se   = (const int*)d_in[4];
  const float* nemb = (const float*)d_in[5];
  const float* lemb = (const float*)d_in[6];
  const float* gw   = (const float*)d_in[7];
  const float* gb   = (const float*)d_in[8];
  const float* lw   = (const float*)d_in[9];
  const float* lb   = (const float*)d_in[10];

  float* ws  = (float*)d_ws;
  float* PT1 = ws;                           // 512*16384  = 8,388,608
  float* PT2 = PT1 + (size_t)NP1 * 16384;    // 1024*16384 = 16,777,216
  float* T1  = PT2 + (size_t)NP2 * 16384;    // 16,384
  float* T2  = T1 + 16384;                   // 16,384
  float* cs  = T2 + 16384;                   // 128
  float* Gg  = cs + 128;                     // 16,384
  float* FEg = Gg + 16384;                   // 16,384
  float* W12 = FEg + 16384;                  // 12,800
  ushort* WThi = (ushort*)(W12 + 12800);     // 28,672 ushorts (16B-aligned)
  ushort* WTlo = WThi + 112 * 256;           // 28,672 ushorts
  float* SEb = (float*)(WTlo + 112 * 256);   // 16,384
  float* FAb = SEb + 16384;                  // 16,384
  float* FFb = FAb + 16384;                  // 16,384

  float* pred = (float*)d_out;
  float* X    = pred + NSEDGE;
  // Abf8 (25.6 MB fp8) lives in the X region of d_out (overwritten by k_x).
  unsigned char* Abf8 = (unsigned char*)X;
  // Xbf (51.2 MB bf16) lives in the PT1/PT2 region (dead after k_reduce).
  ushort* Xbf = (ushort*)PT1;

  // zero T1, T2, cs (contiguous; atomically accumulated)
  hipMemsetAsync(T1, 0, (size_t)(16384 * 2 + 128) * sizeof(float), stream);

  k_abf<<<2048, 256, 0, stream>>>(A, Abf8, cs);
  k_t1<<<NP1, 256, 0, stream>>>(A, lf, nf, lemb, nemb, PT1);
  k_t2<<<NP2, 256, 0, stream>>>(Abf8, ei, PT2);
  k_reduce<<<2 * 64 * PSPLIT, 256, 0, stream>>>(PT1, PT2, T1, T2);
  // tiny 128x128 chain, each stage parallel across blocks
  k_se<<<64, 256, 0, stream>>>(T1, cs, SEb);
  k_mm1<<<128, 128, 0, stream>>>(SEb, gw, cs, Gg);
  k_mm2<<<128, 128, 0, stream>>>(T2, Gg, cs, gb, FAb);
  k_soft<<<1, 128, 0, stream>>>(FAb);
  k_mm3<<<128, 128, 0, stream>>>(FAb, SEb, FEg);
  k_mm4<<<128, 128, 0, stream>>>(FAb, FEg, FFb);
  k_w12<<<128, 128, 0, stream>>>(SEb, FFb, lw, cs, W12);
  k_wt<<<112, 256, 0, stream>>>(lw, W12, WThi, WTlo);
  k_x<<<(ROADN + 511) / 512, 1024, 0, stream>>>(A, lf, nf, lemb, nemb, lb, WThi, WTlo, X, Xbf);
  k_pred<<<(NSEDGE * 16) / 256, 256, 0, stream>>>(Xbf, se, pred);
}